// Round 9
// baseline (570.443 us; speedup 1.0000x reference)
//
#include <hip/hip_runtime.h>
#include <hip/hip_bf16.h>
#include <math.h>

#define NH 8
#define DH 40
#define CCH 320
#define SCALE 0.15811388300841897f

typedef __attribute__((ext_vector_type(8))) short short8;
typedef __attribute__((ext_vector_type(4))) float float4v;

static __device__ __forceinline__ unsigned short f2bf(float x) {
  __hip_bfloat16 t = __float2bfloat16(x);
  return *reinterpret_cast<unsigned short*>(&t);
}

// async global->LDS, 16B per lane. LDS dest must be wave-uniform base; lane writes base+lane*16.
static __device__ __forceinline__ void gload16(const void* g, void* l) {
  __builtin_amdgcn_global_load_lds((__attribute__((address_space(1))) void*)g,
                                   (__attribute__((address_space(3))) void*)l, 16, 0, 0);
}

// ---------------- GroupNorm (32 groups, eps 1e-6) + transpose to (B,HW,C), bf16 out ----------------
__global__ __launch_bounds__(256) void gn_kernel(const float* __restrict__ x,
                                                 const float* __restrict__ w,
                                                 const float* __restrict__ b,
                                                 unsigned short* __restrict__ out) {
  int batch = blockIdx.x >> 5;
  int g = blockIdx.x & 31;
  const int CPG = 10;
  const float* xp = x + ((size_t)batch * CCH + g * CPG) * 1024;
  float s = 0.f, ss = 0.f;
  for (int i = threadIdx.x; i < CPG * 1024; i += 256) { float v = xp[i]; s += v; ss += v * v; }
  __shared__ float r1[256], r2[256];
  r1[threadIdx.x] = s; r2[threadIdx.x] = ss; __syncthreads();
  for (int off = 128; off > 0; off >>= 1) {
    if (threadIdx.x < off) { r1[threadIdx.x] += r1[threadIdx.x + off]; r2[threadIdx.x] += r2[threadIdx.x + off]; }
    __syncthreads();
  }
  float mu = r1[0] * (1.f / 10240.f);
  float var = r2[0] * (1.f / 10240.f) - mu * mu;
  float inv = rsqrtf(var + 1e-6f);
  for (int i = threadIdx.x; i < CPG * 1024; i += 256) {
    int ci = i >> 10; int hw = i & 1023; int c = g * CPG + ci;
    float v = (xp[i] - mu) * inv * w[c] + b[c];
    out[((size_t)batch * 1024 + hw) * CCH + c] = f2bf(v);
  }
}

// ---------------- LayerNorm over C=320, eps 1e-5, one wave per row (4 rows/block), bf16 out ----------------
__global__ __launch_bounds__(256) void ln_kernel(const float* __restrict__ x,
                                                 const float* __restrict__ w,
                                                 const float* __restrict__ b,
                                                 unsigned short* __restrict__ out, int M) {
  int row = blockIdx.x * 4 + (threadIdx.x >> 6);
  if (row >= M) return;
  const float* xp = x + (size_t)row * CCH;
  int lane = threadIdx.x & 63;
  float v[5]; float s = 0.f;
#pragma unroll
  for (int i = 0; i < 5; i++) { v[i] = xp[lane + 64 * i]; s += v[i]; }
#pragma unroll
  for (int o = 32; o > 0; o >>= 1) s += __shfl_xor(s, o);
  float mu = s * (1.f / 320.f);
  float ss = 0.f;
#pragma unroll
  for (int i = 0; i < 5; i++) { float d = v[i] - mu; ss += d * d; }
#pragma unroll
  for (int o = 32; o > 0; o >>= 1) ss += __shfl_xor(ss, o);
  float inv = rsqrtf(ss * (1.f / 320.f) + 1e-5f);
  unsigned short* op = out + (size_t)row * CCH;
#pragma unroll
  for (int i = 0; i < 5; i++) { int c = lane + 64 * i; op[c] = f2bf((v[i] - mu) * inv * w[c] + b[c]); }
}

// ---------------- weight transpose+convert: W(KxN f32) -> Wt(NxK bf16) ----------------
struct WTab {
  const float* src[16];
  unsigned short* dst[16];
  int Kd[16];
  int Nd[16];
  int perm[16];
  int tstart[17];
  float* lz;   // loss accumulator to zero
};
__global__ __launch_bounds__(256) void wconv_kernel(WTab t) {
  __shared__ float tile[32][33];
  if (blockIdx.x == 0 && threadIdx.x == 0) *t.lz = 0.f;
  int gid = blockIdx.x;
  int w = 0;
  while (w < 15 && gid >= t.tstart[w + 1]) w++;
  int local = gid - t.tstart[w];
  int K = t.Kd[w], N = t.Nd[w];
  int ntx = (N + 31) >> 5;
  int bx = local % ntx, by = local / ntx;
  int nb = bx * 32, kb = by * 32;
  const float* src = t.src[w];
  unsigned short* dst = t.dst[w];
  int doperm = t.perm[w];
  int half = N >> 1;
  int tx = threadIdx.x & 31, ty = threadIdx.x >> 5;
  for (int i = ty; i < 32; i += 8) {
    int k = kb + i, n = nb + tx;
    tile[i][tx] = (k < K && n < N) ? src[(size_t)k * N + n] : 0.f;
  }
  __syncthreads();
  for (int i = ty; i < 32; i += 8) {
    int n = nb + i, k = kb + tx;
    if (n < N && k < K) {
      int nd = n;
      if (doperm) {
        if (n < half) nd = (n >> 5) * 64 + (n & 31);
        else { int c = n - half; nd = (c >> 5) * 64 + 32 + (c & 31); }
      }
      dst[(size_t)nd * K + k] = f2bf(tile[tx][i]);
    }
  }
}

// ---------------- fused LayerNorm + bf16 MFMA GEMM 64x64, K=320 fixed ----------------
// A: f32 (M x 320); LN applied during staging. M%64==0, N%64==0. bf16 out, no bias.
__global__ __launch_bounds__(256) void lngemm64_kernel(const float* __restrict__ A,
                                                       const float* __restrict__ lnw,
                                                       const float* __restrict__ lnb,
                                                       const unsigned short* __restrict__ Bt,
                                                       unsigned short* __restrict__ outp,
                                                       int M, int N) {
  __shared__ unsigned short As[64][328];
  __shared__ unsigned short Bsd[2][64][32];
  __shared__ float Wf[320], Bf[320];
  __shared__ float Mu[64], Iv[64];
  const int K = 320;
  int tid = threadIdx.x;
  int lane = tid & 63;
  int wv = tid >> 6;
  int quad = lane >> 4;
  int col = lane & 15;
  int m0 = blockIdx.y * 64;
  int n0 = blockIdx.x * 64;
  const unsigned short* bp0 = Bt + (size_t)(n0 + (tid >> 2)) * K + (tid & 3) * 8;
  gload16(bp0, ((char*)Bsd[0]) + wv * 1024);
  for (int i = tid; i < 320; i += 256) { Wf[i] = lnw[i]; Bf[i] = lnb[i]; }
  int l32 = tid & 31;
  int rsub = tid >> 5;
  for (int it = 0; it < 8; it++) {
    int r = it * 8 + rsub;
    const float* ap = A + (size_t)(m0 + r) * K;
    float s = 0.f, ss = 0.f;
#pragma unroll
    for (int j = 0; j < 10; j++) { float v = ap[l32 + j * 32]; s += v; ss += v * v; }
#pragma unroll
    for (int o = 16; o > 0; o >>= 1) { s += __shfl_xor(s, o); ss += __shfl_xor(ss, o); }
    if (l32 == 0) {
      float mu = s * (1.f / 320.f);
      Mu[r] = mu;
      Iv[r] = rsqrtf(ss * (1.f / 320.f) - mu * mu + 1e-5f);
    }
  }
  __syncthreads();
#pragma unroll 4
  for (int i = 0; i < 20; i++) {
    int cc = i * 256 + tid;
    int r = cc / 80, c4 = cc - r * 80;
    int c = c4 * 4;
    float4 v = *(const float4*)(A + (size_t)(m0 + r) * K + c);
    float mu = Mu[r], iv = Iv[r];
    ushort4 o;
    o.x = f2bf((v.x - mu) * iv * Wf[c] + Bf[c]);
    o.y = f2bf((v.y - mu) * iv * Wf[c + 1] + Bf[c + 1]);
    o.z = f2bf((v.z - mu) * iv * Wf[c + 2] + Bf[c + 2]);
    o.w = f2bf((v.w - mu) * iv * Wf[c + 3] + Bf[c + 3]);
    *(ushort4*)&As[r][c] = o;
  }
  __syncthreads();
  float4v acc[4];
  float4v zero = {0.f, 0.f, 0.f, 0.f};
#pragma unroll
  for (int j = 0; j < 4; j++) acc[j] = zero;
  for (int t = 0; t < 10; t++) {
    if (t < 9) gload16(bp0 + (t + 1) * 32, ((char*)Bsd[(t + 1) & 1]) + wv * 1024);
    int k0 = t * 32;
    short8 af = *(short8*)&As[wv * 16 + col][k0 + quad * 8];
#pragma unroll
    for (int j = 0; j < 4; j++) {
      short8 bfr = *(short8*)&Bsd[t & 1][j * 16 + col][quad * 8];
      acc[j] = __builtin_amdgcn_mfma_f32_16x16x32_bf16(af, bfr, acc[j], 0, 0, 0);
    }
    __syncthreads();
  }
#pragma unroll
  for (int j = 0; j < 4; j++) {
    int n = n0 + j * 16 + col;
#pragma unroll
    for (int r = 0; r < 4; r++) {
      int m = m0 + wv * 16 + quad * 4 + r;
      outp[(size_t)m * N + n] = f2bf(acc[j][r]);
    }
  }
}

// ---------------- fused split-K(8) merge + o-proj GEMM 64x64 (N=K=320), f32 out += res(in place h) ----------------
__global__ __launch_bounds__(256) void mergegemm64_kernel(const float* __restrict__ Opart,
                                                          const float* __restrict__ mpart,
                                                          const float* __restrict__ lpart,
                                                          const unsigned short* __restrict__ Bt,
                                                          const float* __restrict__ bias,
                                                          float* __restrict__ h, int M) {
  __shared__ unsigned short As[64][328];
  __shared__ unsigned short Bsd[2][64][32];
  const int K = 320;
  int tid = threadIdx.x;
  int lane = tid & 63;
  int wv = tid >> 6;
  int quad = lane >> 4;
  int col = lane & 15;
  int m0 = blockIdx.y * 64;
  int n0 = blockIdx.x * 64;
  const unsigned short* bp0 = Bt + (size_t)(n0 + (tid >> 2)) * K + (tid & 3) * 8;
  gload16(bp0, ((char*)Bsd[0]) + wv * 1024);
  // merge-stage A: 64 rows x 40 8-elem chunks = 2560 chunks, 8 split partials each
#pragma unroll
  for (int i = 0; i < 10; i++) {
    int cc = i * 256 + tid;
    int r = cc / 40, c8 = cc - r * 40;
    int c = c8 * 8;
    int hh = c / 40;
    int d = c - hh * 40;
    int m = m0 + r, b = m >> 10, q = m & 1023;
    size_t ri = ((size_t)(b * NH + hh) * 1024 + q) * 8;
    float mm[8];
#pragma unroll
    for (int s2 = 0; s2 < 8; s2++) mm[s2] = mpart[ri + s2];
    float Mx = mm[0];
#pragma unroll
    for (int s2 = 1; s2 < 8; s2++) Mx = fmaxf(Mx, mm[s2]);
    float wgt[8];
    float L = 0.f;
#pragma unroll
    for (int s2 = 0; s2 < 8; s2++) { wgt[s2] = __expf(mm[s2] - Mx); L += lpart[ri + s2] * wgt[s2]; }
    float inv = 1.f / L;
    float a0 = 0.f, a1 = 0.f, a2 = 0.f, a3 = 0.f, e0 = 0.f, e1 = 0.f, e2 = 0.f, e3 = 0.f;
#pragma unroll
    for (int s2 = 0; s2 < 8; s2++) {
      float w = wgt[s2] * inv;
      const float* p = Opart + (ri + s2) * DH + d;
      float4 x = *(const float4*)p;
      float4 y = *(const float4*)(p + 4);
      a0 += w * x.x; a1 += w * x.y; a2 += w * x.z; a3 += w * x.w;
      e0 += w * y.x; e1 += w * y.y; e2 += w * y.z; e3 += w * y.w;
    }
    ushort4 u0, u1;
    u0.x = f2bf(a0); u0.y = f2bf(a1); u0.z = f2bf(a2); u0.w = f2bf(a3);
    u1.x = f2bf(e0); u1.y = f2bf(e1); u1.z = f2bf(e2); u1.w = f2bf(e3);
    *(ushort4*)&As[r][c] = u0;
    *(ushort4*)&As[r][c + 4] = u1;
  }
  __syncthreads();
  float4v acc[4];
  float4v zero = {0.f, 0.f, 0.f, 0.f};
#pragma unroll
  for (int j = 0; j < 4; j++) acc[j] = zero;
  for (int t = 0; t < 10; t++) {
    if (t < 9) gload16(bp0 + (t + 1) * 32, ((char*)Bsd[(t + 1) & 1]) + wv * 1024);
    int k0 = t * 32;
    short8 af = *(short8*)&As[wv * 16 + col][k0 + quad * 8];
#pragma unroll
    for (int j = 0; j < 4; j++) {
      short8 bfr = *(short8*)&Bsd[t & 1][j * 16 + col][quad * 8];
      acc[j] = __builtin_amdgcn_mfma_f32_16x16x32_bf16(af, bfr, acc[j], 0, 0, 0);
    }
    __syncthreads();
  }
#pragma unroll
  for (int j = 0; j < 4; j++) {
    int n = n0 + j * 16 + col;
    float bv = bias[n];
#pragma unroll
    for (int r = 0; r < 4; r++) {
      int m = m0 + wv * 16 + quad * 4 + r;
      size_t oi = (size_t)m * 320 + n;
      h[oi] = acc[j][r] + bv + h[oi];
    }
  }
}

// ---------------- bf16 MFMA GEMM 64x64, BK=160; a32: f32 A staging (slow path) ----------------
// omode: 0=f32 out, 1=bf16 out, 2=transpose+residual f32 out, 3=GEGLU epilogue (bf16, width N/2),
//        4=f32 out (+res) to outp AND bf16 mirror to outp2
__global__ __launch_bounds__(256) void mgemm64_kernel(const void* __restrict__ Ap,
                                                      const unsigned short* __restrict__ Bt,
                                                      const float* __restrict__ bias,
                                                      const float* __restrict__ res,
                                                      void* __restrict__ outp,
                                                      void* __restrict__ outp2,
                                                      int M, int N, int K, int a32, int omode) {
  __shared__ unsigned short As[64][160];
  __shared__ unsigned short Bs[64][160];
  int tid = threadIdx.x;
  int lane = tid & 63;
  int wv = tid >> 6;
  int quad = lane >> 4;
  int col = lane & 15;
  int m0 = blockIdx.y * 64;
  int n0 = blockIdx.x * 64;
  float4v acc[4];
  float4v zero = {0.f, 0.f, 0.f, 0.f};
#pragma unroll
  for (int j = 0; j < 4; j++) acc[j] = zero;
  short8 vzero = {0, 0, 0, 0, 0, 0, 0, 0};
  int kfast = (!a32) && ((K % 160) == 0);
  int off[5];
#pragma unroll
  for (int i = 0; i < 5; i++) { int c = i * 256 + tid; int row = c / 20; off[i] = row * K + (c - row * 20) * 8; }
  int wb = (tid & 192) * 16;   // wave*1024: uniform LDS base for this wave's chunk run
  const unsigned short* Ab = (const unsigned short*)Ap + (size_t)m0 * K;
  const unsigned short* Bb = Bt + (size_t)n0 * K;
  for (int k0 = 0; k0 < K; k0 += 160) {
    if (kfast) {
#pragma unroll
      for (int i = 0; i < 5; i++) {
        gload16(Ab + off[i] + k0, ((char*)As) + wb + i * 4096);
        gload16(Bb + off[i] + k0, ((char*)Bs) + wb + i * 4096);
      }
    } else {
#pragma unroll
      for (int i = 0; i < 5; i++) {
        int u = tid + i * 256;            // 0..1279
        int row = u / 20, seg = u - row * 20;
        int k = k0 + seg * 8;
        int m = m0 + row;
        short8 av = vzero;
        if (m < M && k < K) {
          if (a32) {
            const float* Af = (const float*)Ap;
            float4 f0 = *(const float4*)(Af + (size_t)m * K + k);
            float4 f1 = *(const float4*)(Af + (size_t)m * K + k + 4);
            av[0] = (short)f2bf(f0.x); av[1] = (short)f2bf(f0.y);
            av[2] = (short)f2bf(f0.z); av[3] = (short)f2bf(f0.w);
            av[4] = (short)f2bf(f1.x); av[5] = (short)f2bf(f1.y);
            av[6] = (short)f2bf(f1.z); av[7] = (short)f2bf(f1.w);
          } else {
            av = *(const short8*)((const unsigned short*)Ap + (size_t)m * K + k);
          }
        }
        *(short8*)&As[row][seg * 8] = av;
        int n = n0 + row;
        short8 bv = vzero;
        if (n < N && k < K) bv = *(const short8*)(Bt + (size_t)n * K + k);
        *(short8*)&Bs[row][seg * 8] = bv;
      }
    }
    __syncthreads();
#pragma unroll
    for (int kk = 0; kk < 5; kk++) {
      int kq2 = kk * 32 + quad * 8;
      short8 af = *(short8*)&As[wv * 16 + col][kq2];
#pragma unroll
      for (int j = 0; j < 4; j++) {
        short8 bfr = *(short8*)&Bs[j * 16 + col][kq2];
        acc[j] = __builtin_amdgcn_mfma_f32_16x16x32_bf16(af, bfr, acc[j], 0, 0, 0);
      }
    }
    __syncthreads();
  }
  if (omode == 3) {
    // GEGLU: permuted 64-wide weight groups [a(32)|g(32)]; j=0,1 -> 'a', j=2,3 -> 'g'
    int half = N >> 1;
#pragma unroll
    for (int jb = 0; jb < 2; jb++) {
      int nout = (n0 >> 1) + jb * 16 + col;
      float ba = bias[nout];
      float bg = bias[half + nout];
#pragma unroll
      for (int r = 0; r < 4; r++) {
        int m = m0 + wv * 16 + quad * 4 + r;
        if (m < M) {
          float a = acc[jb][r] + ba;
          float g = acc[jb + 2][r] + bg;
          float t2 = tanhf(0.7978845608028654f * (g + 0.044715f * g * g * g));
          ((unsigned short*)outp)[(size_t)m * half + nout] = f2bf(a * (0.5f * g * (1.f + t2)));
        }
      }
    }
    return;
  }
#pragma unroll
  for (int j = 0; j < 4; j++) {
    int n = n0 + j * 16 + col;
    if (n >= N) continue;
    float bv = bias ? bias[n] : 0.f;
#pragma unroll
    for (int r = 0; r < 4; r++) {
      int m = m0 + wv * 16 + quad * 4 + r;
      if (m < M) {
        float v = acc[j][r] + bv;
        if (omode == 2) {
          int bq = m >> 10, hw = m & 1023;
          size_t oi = ((size_t)bq * N + n) * 1024 + hw;
          ((float*)outp)[oi] = v + res[oi];
        } else {
          if (res) v += res[(size_t)m * N + n];
          if (omode == 1) ((unsigned short*)outp)[(size_t)m * N + n] = f2bf(v);
          else {
            ((float*)outp)[(size_t)m * N + n] = v;
            if (omode == 4) ((unsigned short*)outp2)[(size_t)m * N + n] = f2bf(v);
          }
        }
      }
    }
  }
}

// ---------------- split-K(8) MFMA flash attention: 1024 keys, 8 splits of 128 ----------------
#define VSTR 72
__global__ __launch_bounds__(256) void mfattns_kernel(const unsigned short* __restrict__ qp, int qstr,
                                                      const unsigned short* __restrict__ kp, int kstr,
                                                      const unsigned short* __restrict__ vp, int vstr,
                                                      const float* __restrict__ bias,
                                                      float* __restrict__ Opart,
                                                      float* __restrict__ mpart,
                                                      float* __restrict__ lpart) {
  __shared__ unsigned short Ks[64 * 56];
  __shared__ unsigned short Vt[48 * VSTR];
  __shared__ unsigned short Ps[4][16 * 72];
  int tid = threadIdx.x;
  int lane = tid & 63;
  int wv = tid >> 6;
  int quad = lane >> 4;
  int col = lane & 15;
  int bid = blockIdx.x;
  int split = bid & 7;
  int qt = (bid >> 3) & 15;
  int h = (bid >> 7) & 7;
  int b = bid >> 10;

  short8 zero8 = {0, 0, 0, 0, 0, 0, 0, 0};
  int qrow = qt * 64 + wv * 16 + col;
  const unsigned short* qbase = qp + (size_t)(b * 1024 + qrow) * qstr + h * DH;
  short8 qf0 = *(const short8*)(qbase + quad * 8);
  short8 qf1 = (quad == 0) ? *(const short8*)(qbase + 32) : zero8;

  float4v Oacc[3];
  float4v fzero = {0.f, 0.f, 0.f, 0.f};
  Oacc[0] = fzero; Oacc[1] = fzero; Oacc[2] = fzero;
  float mr[4] = {-3.4e38f, -3.4e38f, -3.4e38f, -3.4e38f};
  float lr[4] = {0.f, 0.f, 0.f, 0.f};

  for (int kt = split * 2; kt < split * 2 + 2; kt++) {
    int kb = kt * 64;
    __syncthreads();
    for (int u = tid; u < 384; u += 256) {
      int key = u / 6, s = u - key * 6;
      short8 kv8 = zero8;
      if (s < 5) kv8 = *(const short8*)(kp + (size_t)(b * 1024 + kb + key) * kstr + h * DH + s * 8);
      *(short8*)&Ks[key * 56 + s * 8] = kv8;
    }
    for (int u = tid; u < 384; u += 256) {
      int s = u >> 6, key = u & 63;
      short8 vv8 = zero8;
      if (s < 5) vv8 = *(const short8*)(vp + (size_t)(b * 1024 + kb + key) * vstr + h * DH + s * 8);
#pragma unroll
      for (int j = 0; j < 8; j++) Vt[(s * 8 + j) * VSTR + key] = (unsigned short)vv8[j];
    }
    __syncthreads();

    float4v sf[4];
#pragma unroll
    for (int jb = 0; jb < 4; jb++) {
      const unsigned short* krow = &Ks[(jb * 16 + col) * 56];
      short8 bk0 = *(const short8*)(krow + quad * 8);
      short8 bk1 = (quad == 0) ? *(const short8*)(krow + 32) : zero8;
      float4v s = fzero;
      s = __builtin_amdgcn_mfma_f32_16x16x32_bf16(qf0, bk0, s, 0, 0, 0);
      s = __builtin_amdgcn_mfma_f32_16x16x32_bf16(qf1, bk1, s, 0, 0, 0);
      float bv = bias ? bias[b * 1024 + kb + jb * 16 + col] : 0.f;
#pragma unroll
      for (int r = 0; r < 4; r++) s[r] = s[r] * SCALE + bv;
      sf[jb] = s;
    }
    float tmax[4];
#pragma unroll
    for (int r = 0; r < 4; r++) {
      float t = fmaxf(fmaxf(sf[0][r], sf[1][r]), fmaxf(sf[2][r], sf[3][r]));
#pragma unroll
      for (int o = 1; o < 16; o <<= 1) t = fmaxf(t, __shfl_xor(t, o));
      tmax[r] = t;
    }
    float al[4];
#pragma unroll
    for (int r = 0; r < 4; r++) {
      float mnew = fmaxf(mr[r], tmax[r]);
      al[r] = __expf(mr[r] - mnew);
      mr[r] = mnew;
      lr[r] *= al[r];
    }
#pragma unroll
    for (int nb = 0; nb < 3; nb++)
#pragma unroll
      for (int r = 0; r < 4; r++) Oacc[nb][r] *= al[r];
    float rs[4] = {0.f, 0.f, 0.f, 0.f};
#pragma unroll
    for (int jb = 0; jb < 4; jb++) {
#pragma unroll
      for (int r = 0; r < 4; r++) {
        float p = __expf(sf[jb][r] - mr[r]);
        rs[r] += p;
        Ps[wv][(quad * 4 + r) * 72 + jb * 16 + col] = f2bf(p);
      }
    }
#pragma unroll
    for (int r = 0; r < 4; r++) {
      float t = rs[r];
#pragma unroll
      for (int o = 1; o < 16; o <<= 1) t += __shfl_xor(t, o);
      lr[r] += t;
    }
#pragma unroll
    for (int kc = 0; kc < 2; kc++) {
      int koff = kc * 32 + quad * 8;
      short8 pa = *(const short8*)&Ps[wv][col * 72 + koff];
#pragma unroll
      for (int nb = 0; nb < 3; nb++) {
        short8 vb = *(const short8*)&Vt[(nb * 16 + col) * VSTR + koff];
        Oacc[nb] = __builtin_amdgcn_mfma_f32_16x16x32_bf16(pa, vb, Oacc[nb], 0, 0, 0);
      }
    }
  }
#pragma unroll
  for (int r = 0; r < 4; r++) {
    int qo = qt * 64 + wv * 16 + quad * 4 + r;
    size_t rowidx = (size_t)(b * NH + h) * 1024 + qo;
    float* orow = Opart + (rowidx * 8 + split) * DH;
#pragma unroll
    for (int nb = 0; nb < 3; nb++) {
      int d = nb * 16 + col;
      if (d < DH) orow[d] = Oacc[nb][r];
    }
    if (col == 0) {
      mpart[rowidx * 8 + split] = mr[r];
      lpart[rowidx * 8 + split] = lr[r];
    }
  }
}

// ---------------- MFMA cross-attention Lk=77 (bf16 in, bf16 out) ----------------
// probs written transposed [(b-2)*8+h][77][1024], batches 2..3 only (the only consumers).
#define CVSTR 104
__global__ __launch_bounds__(256) void cattnm_kernel(const unsigned short* __restrict__ qp,
                                                     const unsigned short* __restrict__ kvp,
                                                     unsigned short* __restrict__ op,
                                                     float* __restrict__ probs) {
  __shared__ unsigned short Ks[80 * 56];
  __shared__ unsigned short Vt[48 * CVSTR];
  __shared__ unsigned short Ps[4][16 * 104];
  int tid = threadIdx.x;
  int lane = tid & 63;
  int wv = tid >> 6;
  int quad = lane >> 4;
  int col = lane & 15;
  int bid = blockIdx.x;
  int qt = bid & 15;
  int h = (bid >> 4) & 7;
  int b = bid >> 7;

  short8 zero8 = {0, 0, 0, 0, 0, 0, 0, 0};
  for (int u = tid; u < 480; u += 256) {
    int key = u / 6, s = u - key * 6;
    short8 v8 = zero8;
    if (s < 5 && key < 77) v8 = *(const short8*)(kvp + (size_t)(b * 77 + key) * 640 + h * DH + s * 8);
    *(short8*)&Ks[key * 56 + s * 8] = v8;
  }
  for (int u = tid; u < 576; u += 256) {
    int s = u / 96, key = u - s * 96;
    short8 v8 = zero8;
    if (s < 5 && key < 77) v8 = *(const short8*)(kvp + (size_t)(b * 77 + key) * 640 + 320 + h * DH + s * 8);
#pragma unroll
    for (int j = 0; j < 8; j++) Vt[(s * 8 + j) * CVSTR + key] = (unsigned short)v8[j];
  }
  int qrow = qt * 64 + wv * 16 + col;
  const unsigned short* qbase = qp + (size_t)(b * 1024 + qrow) * CCH + h * DH;
  short8 qf0 = *(const short8*)(qbase + quad * 8);
  short8 qf1 = (quad == 0) ? *(const short8*)(qbase + 32) : zero8;
  __syncthreads();

  float4v fzero = {0.f, 0.f, 0.f, 0.f};
  float4v sf[5];
#pragma unroll
  for (int jb = 0; jb < 5; jb++) {
    const unsigned short* krow = &Ks[(jb * 16 + col) * 56];
    short8 bk0 = *(const short8*)(krow + quad * 8);
    short8 bk1 = (quad == 0) ? *(const short8*)(krow + 32) : zero8;
    float4v s = fzero;
    s = __builtin_amdgcn_mfma_f32_16x16x32_bf16(qf0, bk0, s, 0, 0, 0);
    s = __builtin_amdgcn_mfma_f32_16x16x32_bf16(qf1, bk1, s, 0, 0, 0);
    int key = jb * 16 + col;
    float msk = (key < 77) ? 0.f : -3.4e38f;
#pragma unroll
    for (int r = 0; r < 4; r++) s[r] = s[r] * SCALE + msk;
    sf[jb] = s;
  }
  float inv[4];
#pragma unroll
  for (int r = 0; r < 4; r++) {
    float t = sf[0][r];
#pragma unroll
    for (int jb = 1; jb < 5; jb++) t = fmaxf(t, sf[jb][r]);
#pragma unroll
    for (int o = 1; o < 16; o <<= 1) t = fmaxf(t, __shfl_xor(t, o));
    float sum = 0.f;
#pragma unroll
    for (int jb = 0; jb < 5; jb++) { float e = __expf(sf[jb][r] - t); sf[jb][r] = e; sum += e; }
#pragma unroll
    for (int o = 1; o < 16; o <<= 1) sum += __shfl_xor(sum, o);
    inv[r] = 1.f / sum;
  }
#pragma unroll
  for (int jb = 0; jb < 5; jb++) {
    int key = jb * 16 + col;
    float4v pv;
#pragma unroll
    for (int r = 0; r < 4; r++) {
      float p = sf[jb][r] * inv[r];
      Ps[wv][(quad * 4 + r) * 104 + jb * 16 + col] = f2bf(p);
      pv[r] = p;
    }
    if (b >= 2 && key < 77) {
      size_t pi = ((size_t)((b - 2) * NH + h) * 77 + key) * 1024 + qt * 64 + wv * 16 + quad * 4;
      *(float4v*)&probs[pi] = pv;
    }
  }
  float4v Oacc[3];
  Oacc[0] = fzero; Oacc[1] = fzero; Oacc[2] = fzero;
#pragma unroll
  for (int kc = 0; kc < 3; kc++) {
    int koff = kc * 32 + quad * 8;
    short8 pa = (koff < 80) ? *(const short8*)&Ps[wv][col * 104 + koff] : zero8;
#pragma unroll
    for (int nb = 0; nb < 3; nb++) {
      short8 vb = *(const short8*)&Vt[(nb * 16 + col) * CVSTR + koff];
      Oacc[nb] = __builtin_amdgcn_mfma_f32_16x16x32_bf16(pa, vb, Oacc[nb], 0, 0, 0);
    }
  }
#pragma unroll
  for (int r = 0; r < 4; r++) {
    int qo = qt * 64 + wv * 16 + quad * 4 + r;
    unsigned short* orow = op + (size_t)(b * 1024 + qo) * CCH + h * DH;
#pragma unroll
    for (int nb = 0; nb < 3; nb++) {
      int d = nb * 16 + col;
      if (d < DH) orow[d] = f2bf(Oacc[nb][r]);
    }
  }
}

// ---------------- fused extract + loss + otsu: single-pass, register-resident ----------------
// pT layout: [(b-2)*8+h][77][1024]; reads are coalesced rows.
__global__ __launch_bounds__(256) void eol_kernel(const float* __restrict__ pT,
                                                  const int* __restrict__ phb, const int* __restrict__ pht,
                                                  const int* __restrict__ eob, const int* __restrict__ eot,
                                                  float* __restrict__ mask,
                                                  float* __restrict__ lossout) {
  __shared__ float S[4][24];
  __shared__ float shthr;
  int i = blockIdx.x, tid = threadIdx.x;
  int lane = tid & 63, wv = tid >> 6;
  int pb = phb[i], pt = pht[i], eb = eob[i], et = eot[i];
  float x[4], y[4];
#pragma unroll
  for (int j = 0; j < 4; j++) {
    int q = tid + 256 * j;
    float s1 = 0.f, s2 = 0.f;
#pragma unroll
    for (int hh = 0; hh < NH; hh++) {
      s1 += pT[((size_t)(pb * NH + hh) * 77 + pt) * 1024 + q];
      s2 += pT[((size_t)(eb * NH + hh) * 77 + et) * 1024 + q];
    }
    x[j] = s1 * 0.125f;
    y[j] = s2 * 0.125f;
  }
  float mx = fmaxf(fmaxf(x[0], x[1]), fmaxf(x[2], x[3]));
  float me = fmaxf(fmaxf(y[0], y[1]), fmaxf(y[2], y[3]));
  float mn = fminf(fminf(x[0], x[1]), fminf(x[2], x[3]));
  float sx = x[0] + x[1] + x[2] + x[3];
#pragma unroll
  for (int o = 32; o > 0; o >>= 1) {
    mx = fmaxf(mx, __shfl_xor(mx, o));
    me = fmaxf(me, __shfl_xor(me, o));
    mn = fminf(mn, __shfl_xor(mn, o));
    sx += __shfl_xor(sx, o);
  }
  if (lane == 0) { S[wv][0] = mx; S[wv][1] = me; S[wv][2] = mn; S[wv][3] = sx; }
  __syncthreads();
  mx = fmaxf(fmaxf(S[0][0], S[1][0]), fmaxf(S[2][0], S[3][0]));
  me = fmaxf(fmaxf(S[0][1], S[1][1]), fmaxf(S[2][1], S[3][1]));
  mn = fminf(fminf(S[0][2], S[1][2]), fminf(S[2][2], S[3][2]));
  sx = S[0][3] + S[1][3] + S[2][3] + S[3][3];
  float invmp = 1.f / mx, invme = 1.f / me;
  float inv = 1.f / (mx - mn);
  float lp = 0.f;
  float cnt[10], sm[10];
#pragma unroll
  for (int t = 0; t < 10; t++) { cnt[t] = 0.f; sm[t] = 0.f; }
#pragma unroll
  for (int j = 0; j < 4; j++) {
    float d = x[j] * invmp - y[j] * invme;
    lp += d * d;
    float v = (x[j] - mn) * inv;
#pragma unroll
    for (int t = 0; t < 10; t++) {
      if (v < t * 0.1f) { cnt[t] += 1.f; sm[t] += v; }
    }
  }
#pragma unroll
  for (int o = 32; o > 0; o >>= 1) {
    lp += __shfl_xor(lp, o);
#pragma unroll
    for (int t = 0; t < 10; t++) { cnt[t] += __shfl_xor(cnt[t], o); sm[t] += __shfl_xor(sm[t], o); }
  }
  __syncthreads();
  if (lane == 0) {
    S[wv][0] = lp;
#pragma unroll
    for (int t = 0; t < 10; t++) { S[wv][1 + t] = cnt[t]; S[wv][11 + t] = sm[t]; }
  }
  __syncthreads();
  if (tid == 0) {
    float lpt = S[0][0] + S[1][0] + S[2][0] + S[3][0];
    atomicAdd(lossout, lpt * (1.f / 2048.f));
    float total = (sx - 1024.f * mn) * inv;
    float gmax = -3.4e38f; int best = 0;
    for (int t = 0; t < 10; t++) {
      float c_low = S[0][1 + t] + S[1][1 + t] + S[2][1 + t] + S[3][1 + t];
      float s_low = S[0][11 + t] + S[1][11 + t] + S[2][11 + t] + S[3][11 + t];
      float c_high = 1024.f - c_low;
      float g;
      if (c_low > 0.f && c_high > 0.f) {
        float mu_l = s_low / c_low;
        float mu_h = (total - s_low) / c_high;
        float dd = mu_l - mu_h;
        g = (c_low * (1.f / 1024.f)) * (c_high * (1.f / 1024.f)) * dd * dd;
      } else g = -3.4e38f;
      if (g > gmax) { gmax = g; best = t; }
    }
    shthr = (gmax > 0.f) ? best * 0.1f : 0.f;
  }
  __syncthreads();
  float thr = shthr;
#pragma unroll
  for (int j = 0; j < 4; j++) {
    int q = tid + 256 * j;
    float v = (x[j] - mn) * inv;
    mask[i * 1024 + q] = (v < thr) ? 0.f : ((v > thr) ? 1.f : v);
  }
}

extern "C" void kernel_launch(void* const* d_in, const int* in_sizes, int n_in,
                              void* d_out, int out_size, void* d_ws, size_t ws_size,
                              hipStream_t stream) {
  auto F = [&](int i) { return (const float*)d_in[i]; };
  auto I = [&](int i) { return (const int*)d_in[i]; };

  float* ws = (float*)d_ws;
  float* h    = ws;                       // 1310720
  float* ffb  = h    + 1310720;           // attn split partials: 10485760 floats
  float* p2   = ffb  + 10485760;          // probs^T: 16*77*1024 = 1261568 (region sized 2523136)
  float* mask = p2   + 2523136;           // 2048

  float* Opart = ffb;                       // 32768*8*40 = 10485760 (fills ffb region)
  float* mpart = p2 + 1261568;              // 262144 (p2-region slack)
  float* lpart = mpart + 262144;            // 262144

  // bf16 region
  unsigned short* b16   = (unsigned short*)(mask + 2048);
  unsigned short* lnb16 = b16;                 // 1310720
  unsigned short* attb16= lnb16 + 1310720;     // 1310720
  unsigned short* actb16= attb16 + 1310720;    // 5242880
  unsigned short* qkv16 = actb16 + 5242880;    // 3932160
  unsigned short* q16   = qkv16 + 3932160;     // 1310720
  unsigned short* kv16  = q16 + 1310720;       // 1310720
  unsigned short* hb16  = kv16 + 1310720;      // 1310720 (bf16 mirror of h)
  unsigned short* wptr  = hb16 + 1310720;

  auto walloc = [&](int n) { unsigned short* p = wptr; wptr += n; return p; };
  unsigned short* pin_t  = walloc(102400);
  unsigned short* bqkv_t = walloc(307200);
  unsigned short* bow_t  = walloc(102400);
  unsigned short* bq2_t  = walloc(102400);
  unsigned short* bkv2_t = walloc(491520);
  unsigned short* bo2_t  = walloc(102400);
  unsigned short* bff1_t = walloc(819200);
  unsigned short* bff2_t = walloc(409600);
  unsigned short* iqkv_t = walloc(307200);
  unsigned short* iow_t  = walloc(102400);
  unsigned short* iq2_t  = walloc(102400);
  unsigned short* ikv2_t = walloc(204800);
  unsigned short* io2_t  = walloc(102400);
  unsigned short* iff1_t = walloc(819200);
  unsigned short* iff2_t = walloc(409600);
  unsigned short* pout_t = walloc(102400);

  float* out = (float*)d_out;

  // --- weight conversion table ---
  WTab wt;
  wt.lz = out + 1310720;   // loss slot zeroed by wconv
  int nt = 0, cnt = 0;
  auto addw = [&](const float* s, unsigned short* d, int K, int N, int perm) {
    wt.src[cnt] = s; wt.dst[cnt] = d; wt.Kd[cnt] = K; wt.Nd[cnt] = N; wt.perm[cnt] = perm;
    wt.tstart[cnt] = nt;
    nt += ((K + 31) / 32) * ((N + 31) / 32);
    cnt++;
  };
  addw(F(2), pin_t, 320, 320, 0);
  addw(F(4 + 2), bqkv_t, 320, 960, 0);
  addw(F(4 + 3), bow_t, 320, 320, 0);
  addw(F(4 + 7), bq2_t, 320, 320, 0);
  addw(F(4 + 8), bkv2_t, 768, 640, 0);
  addw(F(4 + 9), bo2_t, 320, 320, 0);
  addw(F(4 + 13), bff1_t, 320, 2560, 1);
  addw(F(4 + 15), bff2_t, 1280, 320, 0);
  addw(F(21 + 2), iqkv_t, 320, 960, 0);
  addw(F(21 + 3), iow_t, 320, 320, 0);
  addw(F(21 + 7), iq2_t, 320, 320, 0);
  addw(F(21 + 8), ikv2_t, 320, 640, 0);
  addw(F(21 + 9), io2_t, 320, 320, 0);
  addw(F(21 + 13), iff1_t, 320, 2560, 1);
  addw(F(21 + 15), iff2_t, 1280, 320, 0);
  addw(F(38), pout_t, 320, 320, 0);
  wt.tstart[16] = nt;

  wconv_kernel<<<nt, 256, 0, stream>>>(wt);

  auto gemm64 = [&](const void* A, const unsigned short* Wt, const float* bias,
                    const float* res, void* o, int M, int N, int K, int a32, int omode,
                    void* o2 = nullptr) {
    dim3 g((N + 63) / 64, (M + 63) / 64);
    mgemm64_kernel<<<g, 256, 0, stream>>>(A, Wt, bias, res, o, o2, M, N, K, a32, omode);
  };
  auto lngemm = [&](const float* A, const float* lw, const float* lb,
                    const unsigned short* Wt, unsigned short* o, int M, int N) {
    dim3 g(N / 64, M / 64);
    lngemm64_kernel<<<g, 256, 0, stream>>>(A, lw, lb, Wt, o, M, N);
  };
  auto mergegemm = [&](const unsigned short* Wt, const float* bias, int M) {
    dim3 g(5, M / 64);
    mergegemm64_kernel<<<g, 256, 0, stream>>>(Opart, mpart, lpart, Wt, bias, h, M);
  };

  // GN + transpose -> lnb16 ; pin proj -> h (f32)
  gn_kernel<<<128, 256, 0, stream>>>(F(40), F(0), F(1), lnb16);
  gemm64(lnb16, pin_t, F(3), nullptr, h, 4096, 320, 320, 0, 0);

  auto run_block = [&](int p, int Bx, bool img_block,
                       const unsigned short* qkv_t, const unsigned short* ow_t,
                       const unsigned short* q2_t, const unsigned short* kv2_t,
                       const unsigned short* o2_t, const unsigned short* ff1_t,
                       const unsigned short* ff2_t) {
    int M = Bx * 1024;
    // ln1 -> qkv (plain kfast GEMM) -> split-K(8) mfma flash self-attn -> fused merge+o-proj(+res)
    ln_kernel<<<M / 4, 256, 0, stream>>>(h, F(p + 0), F(p + 1), lnb16, M);
    gemm64(lnb16, qkv_t, nullptr, nullptr, qkv16, M, 960, 320, 0, 1);
    mfattns_kernel<<<Bx * 1024, 256, 0, stream>>>(qkv16, 960, qkv16 + 320, 960, qkv16 + 640, 960,
                                                  nullptr, Opart, mpart, lpart);
    mergegemm(ow_t, F(p + 4), M);
    // fused ln2+q2 ; cross-attn
    lngemm(h, F(p + 5), F(p + 6), q2_t, q16, M, 320);
    if (!img_block) {
      gemm64(F(41), kv2_t, nullptr, nullptr, kv16, Bx * 77, 640, 768, 1, 1);   // f32 A (slow path)
      cattnm_kernel<<<Bx * 128, 256, 0, stream>>>(q16, kv16, attb16, p2);
      gemm64(attb16, o2_t, F(p + 10), h, h, M, 320, 320, 0, 0);
    } else {
      // ctx = h batches 2-3, available as bf16 mirror from block-1 ff2
      gemm64(hb16 + (size_t)2 * 1024 * 320, kv2_t, nullptr, nullptr, kv16, Bx * 1024, 640, 320, 0, 1);
      mfattns_kernel<<<Bx * 1024, 256, 0, stream>>>(q16, 320, kv16, 640, kv16 + 320, 640,
                                                    mask, Opart, mpart, lpart);
      mergegemm(o2_t, F(p + 10), M);
    }
    // ln3 -> ff1 (plain GEMM + GEGLU epilogue) -> ff2 (f32 h + bf16 mirror hb16)
    ln_kernel<<<M / 4, 256, 0, stream>>>(h, F(p + 11), F(p + 12), lnb16, M);
    gemm64(lnb16, ff1_t, F(p + 14), nullptr, actb16, M, 2560, 320, 0, 3);
    gemm64(actb16, ff2_t, F(p + 16), h, h, M, 320, 1280, 0, 4, hb16);
  };

  // Block 1: all 4 batches, ctx = encoder_hidden_states, probs saved (transposed, b>=2 only)
  run_block(4, 4, false, bqkv_t, bow_t, bq2_t, bkv2_t, bo2_t, bff1_t, bff2_t);

  // fused extract + loss + otsu (loss slot zeroed in wconv)
  eol_kernel<<<2, 256, 0, stream>>>(p2, I(42), I(43), I(44), I(45), mask, out + 1310720);

  // Block 2: batches 0-1 in place, ctx = batches 2-3 of h (bf16 mirror), bias = mask
  run_block(21, 2, true, iqkv_t, iow_t, iq2_t, ikv2_t, io2_t, iff1_t, iff2_t);

  // pout proj from bf16 mirror (kfast) with fused transpose + residual epilogue
  gemm64(hb16, pout_t, F(39), F(40), out, 4096, 320, 320, 0, 2);
}

// Round 10
// 532.723 us; speedup vs baseline: 1.0708x; 1.0708x over previous
//
#include <hip/hip_runtime.h>
#include <hip/hip_bf16.h>
#include <math.h>

#define NH 8
#define DH 40
#define CCH 320
#define SCALE 0.15811388300841897f

typedef __attribute__((ext_vector_type(8))) short short8;
typedef __attribute__((ext_vector_type(4))) float float4v;

static __device__ __forceinline__ unsigned short f2bf(float x) {
  __hip_bfloat16 t = __float2bfloat16(x);
  return *reinterpret_cast<unsigned short*>(&t);
}

// async global->LDS, 16B per lane. LDS dest must be wave-uniform base; lane writes base+lane*16.
static __device__ __forceinline__ void gload16(const void* g, void* l) {
  __builtin_amdgcn_global_load_lds((__attribute__((address_space(1))) void*)g,
                                   (__attribute__((address_space(3))) void*)l, 16, 0, 0);
}

// ---------------- GroupNorm (32 groups, eps 1e-6) + transpose to (B,HW,C), bf16 out ----------------
__global__ __launch_bounds__(256) void gn_kernel(const float* __restrict__ x,
                                                 const float* __restrict__ w,
                                                 const float* __restrict__ b,
                                                 unsigned short* __restrict__ out) {
  int batch = blockIdx.x >> 5;
  int g = blockIdx.x & 31;
  const int CPG = 10;
  const float* xp = x + ((size_t)batch * CCH + g * CPG) * 1024;
  float s = 0.f, ss = 0.f;
  for (int i = threadIdx.x; i < CPG * 1024; i += 256) { float v = xp[i]; s += v; ss += v * v; }
  __shared__ float r1[256], r2[256];
  r1[threadIdx.x] = s; r2[threadIdx.x] = ss; __syncthreads();
  for (int off = 128; off > 0; off >>= 1) {
    if (threadIdx.x < off) { r1[threadIdx.x] += r1[threadIdx.x + off]; r2[threadIdx.x] += r2[threadIdx.x + off]; }
    __syncthreads();
  }
  float mu = r1[0] * (1.f / 10240.f);
  float var = r2[0] * (1.f / 10240.f) - mu * mu;
  float inv = rsqrtf(var + 1e-6f);
  for (int i = threadIdx.x; i < CPG * 1024; i += 256) {
    int ci = i >> 10; int hw = i & 1023; int c = g * CPG + ci;
    float v = (xp[i] - mu) * inv * w[c] + b[c];
    out[((size_t)batch * 1024 + hw) * CCH + c] = f2bf(v);
  }
}

// ---------------- LayerNorm over C=320, eps 1e-5, one wave per row (4 rows/block), bf16 out ----------------
__global__ __launch_bounds__(256) void ln_kernel(const float* __restrict__ x,
                                                 const float* __restrict__ w,
                                                 const float* __restrict__ b,
                                                 unsigned short* __restrict__ out, int M) {
  int row = blockIdx.x * 4 + (threadIdx.x >> 6);
  if (row >= M) return;
  const float* xp = x + (size_t)row * CCH;
  int lane = threadIdx.x & 63;
  float v[5]; float s = 0.f;
#pragma unroll
  for (int i = 0; i < 5; i++) { v[i] = xp[lane + 64 * i]; s += v[i]; }
#pragma unroll
  for (int o = 32; o > 0; o >>= 1) s += __shfl_xor(s, o);
  float mu = s * (1.f / 320.f);
  float ss = 0.f;
#pragma unroll
  for (int i = 0; i < 5; i++) { float d = v[i] - mu; ss += d * d; }
#pragma unroll
  for (int o = 32; o > 0; o >>= 1) ss += __shfl_xor(ss, o);
  float inv = rsqrtf(ss * (1.f / 320.f) + 1e-5f);
  unsigned short* op = out + (size_t)row * CCH;
#pragma unroll
  for (int i = 0; i < 5; i++) { int c = lane + 64 * i; op[c] = f2bf((v[i] - mu) * inv * w[c] + b[c]); }
}

// ---------------- weight transpose+convert: W(KxN f32) -> Wt(NxK bf16) ----------------
struct WTab {
  const float* src[16];
  unsigned short* dst[16];
  int Kd[16];
  int Nd[16];
  int perm[16];
  int tstart[17];
  float* lz;   // loss accumulator to zero
};
__global__ __launch_bounds__(256) void wconv_kernel(WTab t) {
  __shared__ float tile[32][33];
  if (blockIdx.x == 0 && threadIdx.x == 0) *t.lz = 0.f;
  int gid = blockIdx.x;
  int w = 0;
  while (w < 15 && gid >= t.tstart[w + 1]) w++;
  int local = gid - t.tstart[w];
  int K = t.Kd[w], N = t.Nd[w];
  int ntx = (N + 31) >> 5;
  int bx = local % ntx, by = local / ntx;
  int nb = bx * 32, kb = by * 32;
  const float* src = t.src[w];
  unsigned short* dst = t.dst[w];
  int doperm = t.perm[w];
  int half = N >> 1;
  int tx = threadIdx.x & 31, ty = threadIdx.x >> 5;
  for (int i = ty; i < 32; i += 8) {
    int k = kb + i, n = nb + tx;
    tile[i][tx] = (k < K && n < N) ? src[(size_t)k * N + n] : 0.f;
  }
  __syncthreads();
  for (int i = ty; i < 32; i += 8) {
    int n = nb + i, k = kb + tx;
    if (n < N && k < K) {
      int nd = n;
      if (doperm) {
        if (n < half) nd = (n >> 5) * 64 + (n & 31);
        else { int c = n - half; nd = (c >> 5) * 64 + 32 + (c & 31); }
      }
      dst[(size_t)nd * K + k] = f2bf(tile[tx][i]);
    }
  }
}

// ---------------- fused LayerNorm + bf16 MFMA GEMM 64x64, K=320 fixed ----------------
// A: f32 (M x 320); LN applied during staging. M%64==0, N%64==0. bf16 out, no bias.
__global__ __launch_bounds__(256) void lngemm64_kernel(const float* __restrict__ A,
                                                       const float* __restrict__ lnw,
                                                       const float* __restrict__ lnb,
                                                       const unsigned short* __restrict__ Bt,
                                                       unsigned short* __restrict__ outp,
                                                       int M, int N) {
  __shared__ unsigned short As[64][328];
  __shared__ unsigned short Bsd[2][64][32];
  __shared__ float Wf[320], Bf[320];
  __shared__ float Mu[64], Iv[64];
  const int K = 320;
  int tid = threadIdx.x;
  int lane = tid & 63;
  int wv = tid >> 6;
  int quad = lane >> 4;
  int col = lane & 15;
  int m0 = blockIdx.y * 64;
  int n0 = blockIdx.x * 64;
  const unsigned short* bp0 = Bt + (size_t)(n0 + (tid >> 2)) * K + (tid & 3) * 8;
  gload16(bp0, ((char*)Bsd[0]) + wv * 1024);
  for (int i = tid; i < 320; i += 256) { Wf[i] = lnw[i]; Bf[i] = lnb[i]; }
  int l32 = tid & 31;
  int rsub = tid >> 5;
  for (int it = 0; it < 8; it++) {
    int r = it * 8 + rsub;
    const float* ap = A + (size_t)(m0 + r) * K;
    float s = 0.f, ss = 0.f;
#pragma unroll
    for (int j = 0; j < 10; j++) { float v = ap[l32 + j * 32]; s += v; ss += v * v; }
#pragma unroll
    for (int o = 16; o > 0; o >>= 1) { s += __shfl_xor(s, o); ss += __shfl_xor(ss, o); }
    if (l32 == 0) {
      float mu = s * (1.f / 320.f);
      Mu[r] = mu;
      Iv[r] = rsqrtf(ss * (1.f / 320.f) - mu * mu + 1e-5f);
    }
  }
  __syncthreads();
#pragma unroll 4
  for (int i = 0; i < 20; i++) {
    int cc = i * 256 + tid;
    int r = cc / 80, c4 = cc - r * 80;
    int c = c4 * 4;
    float4 v = *(const float4*)(A + (size_t)(m0 + r) * K + c);
    float mu = Mu[r], iv = Iv[r];
    ushort4 o;
    o.x = f2bf((v.x - mu) * iv * Wf[c] + Bf[c]);
    o.y = f2bf((v.y - mu) * iv * Wf[c + 1] + Bf[c + 1]);
    o.z = f2bf((v.z - mu) * iv * Wf[c + 2] + Bf[c + 2]);
    o.w = f2bf((v.w - mu) * iv * Wf[c + 3] + Bf[c + 3]);
    *(ushort4*)&As[r][c] = o;
  }
  __syncthreads();
  float4v acc[4];
  float4v zero = {0.f, 0.f, 0.f, 0.f};
#pragma unroll
  for (int j = 0; j < 4; j++) acc[j] = zero;
  for (int t = 0; t < 10; t++) {
    if (t < 9) gload16(bp0 + (t + 1) * 32, ((char*)Bsd[(t + 1) & 1]) + wv * 1024);
    int k0 = t * 32;
    short8 af = *(short8*)&As[wv * 16 + col][k0 + quad * 8];
#pragma unroll
    for (int j = 0; j < 4; j++) {
      short8 bfr = *(short8*)&Bsd[t & 1][j * 16 + col][quad * 8];
      acc[j] = __builtin_amdgcn_mfma_f32_16x16x32_bf16(af, bfr, acc[j], 0, 0, 0);
    }
    __syncthreads();
  }
#pragma unroll
  for (int j = 0; j < 4; j++) {
    int n = n0 + j * 16 + col;
#pragma unroll
    for (int r = 0; r < 4; r++) {
      int m = m0 + wv * 16 + quad * 4 + r;
      outp[(size_t)m * N + n] = f2bf(acc[j][r]);
    }
  }
}

// ---------------- fused split-K merge + o-proj GEMM 64x64 (N=K=320), f32 out += res(in place h) ----------------
__global__ __launch_bounds__(256) void mergegemm64_kernel(const float* __restrict__ Opart,
                                                          const float* __restrict__ mpart,
                                                          const float* __restrict__ lpart,
                                                          const unsigned short* __restrict__ Bt,
                                                          const float* __restrict__ bias,
                                                          float* __restrict__ h, int M) {
  __shared__ unsigned short As[64][328];
  __shared__ unsigned short Bsd[2][64][32];
  const int K = 320;
  int tid = threadIdx.x;
  int lane = tid & 63;
  int wv = tid >> 6;
  int quad = lane >> 4;
  int col = lane & 15;
  int m0 = blockIdx.y * 64;
  int n0 = blockIdx.x * 64;
  const unsigned short* bp0 = Bt + (size_t)(n0 + (tid >> 2)) * K + (tid & 3) * 8;
  gload16(bp0, ((char*)Bsd[0]) + wv * 1024);
  // merge-stage A: 64 rows x 40 8-elem chunks = 2560 chunks
#pragma unroll
  for (int i = 0; i < 10; i++) {
    int cc = i * 256 + tid;
    int r = cc / 40, c8 = cc - r * 40;
    int c = c8 * 8;
    int hh = c / 40;
    int d = c - hh * 40;
    int m = m0 + r, b = m >> 10, q = m & 1023;
    size_t ri = ((size_t)(b * NH + hh) * 1024 + q) * 4;
    float ma = mpart[ri], mb = mpart[ri + 1], mc = mpart[ri + 2], md = mpart[ri + 3];
    float Mx = fmaxf(fmaxf(ma, mb), fmaxf(mc, md));
    float w0 = __expf(ma - Mx), w1 = __expf(mb - Mx), w2 = __expf(mc - Mx), w3 = __expf(md - Mx);
    float L = lpart[ri] * w0 + lpart[ri + 1] * w1 + lpart[ri + 2] * w2 + lpart[ri + 3] * w3;
    float inv = 1.f / L;
    w0 *= inv; w1 *= inv; w2 *= inv; w3 *= inv;
    const float* p0 = Opart + (ri + 0) * DH + d;
    const float* p1 = Opart + (ri + 1) * DH + d;
    const float* p2 = Opart + (ri + 2) * DH + d;
    const float* p3 = Opart + (ri + 3) * DH + d;
    float4 a0 = *(const float4*)p0, a1 = *(const float4*)p1, a2 = *(const float4*)p2, a3 = *(const float4*)p3;
    float4 b0 = *(const float4*)(p0 + 4), b1 = *(const float4*)(p1 + 4), b2 = *(const float4*)(p2 + 4), b3 = *(const float4*)(p3 + 4);
    ushort4 u0, u1;
    u0.x = f2bf(a0.x * w0 + a1.x * w1 + a2.x * w2 + a3.x * w3);
    u0.y = f2bf(a0.y * w0 + a1.y * w1 + a2.y * w2 + a3.y * w3);
    u0.z = f2bf(a0.z * w0 + a1.z * w1 + a2.z * w2 + a3.z * w3);
    u0.w = f2bf(a0.w * w0 + a1.w * w1 + a2.w * w2 + a3.w * w3);
    u1.x = f2bf(b0.x * w0 + b1.x * w1 + b2.x * w2 + b3.x * w3);
    u1.y = f2bf(b0.y * w0 + b1.y * w1 + b2.y * w2 + b3.y * w3);
    u1.z = f2bf(b0.z * w0 + b1.z * w1 + b2.z * w2 + b3.z * w3);
    u1.w = f2bf(b0.w * w0 + b1.w * w1 + b2.w * w2 + b3.w * w3);
    *(ushort4*)&As[r][c] = u0;
    *(ushort4*)&As[r][c + 4] = u1;
  }
  __syncthreads();
  float4v acc[4];
  float4v zero = {0.f, 0.f, 0.f, 0.f};
#pragma unroll
  for (int j = 0; j < 4; j++) acc[j] = zero;
  for (int t = 0; t < 10; t++) {
    if (t < 9) gload16(bp0 + (t + 1) * 32, ((char*)Bsd[(t + 1) & 1]) + wv * 1024);
    int k0 = t * 32;
    short8 af = *(short8*)&As[wv * 16 + col][k0 + quad * 8];
#pragma unroll
    for (int j = 0; j < 4; j++) {
      short8 bfr = *(short8*)&Bsd[t & 1][j * 16 + col][quad * 8];
      acc[j] = __builtin_amdgcn_mfma_f32_16x16x32_bf16(af, bfr, acc[j], 0, 0, 0);
    }
    __syncthreads();
  }
#pragma unroll
  for (int j = 0; j < 4; j++) {
    int n = n0 + j * 16 + col;
    float bv = bias[n];
#pragma unroll
    for (int r = 0; r < 4; r++) {
      int m = m0 + wv * 16 + quad * 4 + r;
      size_t oi = (size_t)m * 320 + n;
      h[oi] = acc[j][r] + bv + h[oi];
    }
  }
}

// ---------------- bf16 MFMA GEMM 64x64, BK=160; a32: f32 A staging (slow path) ----------------
// omode: 0=f32 out, 1=bf16 out, 2=transpose+residual f32 out, 3=GEGLU epilogue (bf16, width N/2),
//        4=f32 out (+res) to outp AND bf16 mirror to outp2
__global__ __launch_bounds__(256) void mgemm64_kernel(const void* __restrict__ Ap,
                                                      const unsigned short* __restrict__ Bt,
                                                      const float* __restrict__ bias,
                                                      const float* __restrict__ res,
                                                      void* __restrict__ outp,
                                                      void* __restrict__ outp2,
                                                      int M, int N, int K, int a32, int omode) {
  __shared__ unsigned short As[64][160];
  __shared__ unsigned short Bs[64][160];
  int tid = threadIdx.x;
  int lane = tid & 63;
  int wv = tid >> 6;
  int quad = lane >> 4;
  int col = lane & 15;
  int m0 = blockIdx.y * 64;
  int n0 = blockIdx.x * 64;
  float4v acc[4];
  float4v zero = {0.f, 0.f, 0.f, 0.f};
#pragma unroll
  for (int j = 0; j < 4; j++) acc[j] = zero;
  short8 vzero = {0, 0, 0, 0, 0, 0, 0, 0};
  int kfast = (!a32) && ((K % 160) == 0);
  int off[5];
#pragma unroll
  for (int i = 0; i < 5; i++) { int c = i * 256 + tid; int row = c / 20; off[i] = row * K + (c - row * 20) * 8; }
  int wb = (tid & 192) * 16;   // wave*1024: uniform LDS base for this wave's chunk run
  const unsigned short* Ab = (const unsigned short*)Ap + (size_t)m0 * K;
  const unsigned short* Bb = Bt + (size_t)n0 * K;
  for (int k0 = 0; k0 < K; k0 += 160) {
    if (kfast) {
#pragma unroll
      for (int i = 0; i < 5; i++) {
        gload16(Ab + off[i] + k0, ((char*)As) + wb + i * 4096);
        gload16(Bb + off[i] + k0, ((char*)Bs) + wb + i * 4096);
      }
    } else {
#pragma unroll
      for (int i = 0; i < 5; i++) {
        int u = tid + i * 256;            // 0..1279
        int row = u / 20, seg = u - row * 20;
        int k = k0 + seg * 8;
        int m = m0 + row;
        short8 av = vzero;
        if (m < M && k < K) {
          if (a32) {
            const float* Af = (const float*)Ap;
            float4 f0 = *(const float4*)(Af + (size_t)m * K + k);
            float4 f1 = *(const float4*)(Af + (size_t)m * K + k + 4);
            av[0] = (short)f2bf(f0.x); av[1] = (short)f2bf(f0.y);
            av[2] = (short)f2bf(f0.z); av[3] = (short)f2bf(f0.w);
            av[4] = (short)f2bf(f1.x); av[5] = (short)f2bf(f1.y);
            av[6] = (short)f2bf(f1.z); av[7] = (short)f2bf(f1.w);
          } else {
            av = *(const short8*)((const unsigned short*)Ap + (size_t)m * K + k);
          }
        }
        *(short8*)&As[row][seg * 8] = av;
        int n = n0 + row;
        short8 bv = vzero;
        if (n < N && k < K) bv = *(const short8*)(Bt + (size_t)n * K + k);
        *(short8*)&Bs[row][seg * 8] = bv;
      }
    }
    __syncthreads();
#pragma unroll
    for (int kk = 0; kk < 5; kk++) {
      int kq2 = kk * 32 + quad * 8;
      short8 af = *(short8*)&As[wv * 16 + col][kq2];
#pragma unroll
      for (int j = 0; j < 4; j++) {
        short8 bfr = *(short8*)&Bs[j * 16 + col][kq2];
        acc[j] = __builtin_amdgcn_mfma_f32_16x16x32_bf16(af, bfr, acc[j], 0, 0, 0);
      }
    }
    __syncthreads();
  }
  if (omode == 3) {
    // GEGLU: permuted 64-wide weight groups [a(32)|g(32)]; j=0,1 -> 'a', j=2,3 -> 'g'
    int half = N >> 1;
#pragma unroll
    for (int jb = 0; jb < 2; jb++) {
      int nout = (n0 >> 1) + jb * 16 + col;
      float ba = bias[nout];
      float bg = bias[half + nout];
#pragma unroll
      for (int r = 0; r < 4; r++) {
        int m = m0 + wv * 16 + quad * 4 + r;
        if (m < M) {
          float a = acc[jb][r] + ba;
          float g = acc[jb + 2][r] + bg;
          float t2 = tanhf(0.7978845608028654f * (g + 0.044715f * g * g * g));
          ((unsigned short*)outp)[(size_t)m * half + nout] = f2bf(a * (0.5f * g * (1.f + t2)));
        }
      }
    }
    return;
  }
#pragma unroll
  for (int j = 0; j < 4; j++) {
    int n = n0 + j * 16 + col;
    if (n >= N) continue;
    float bv = bias ? bias[n] : 0.f;
#pragma unroll
    for (int r = 0; r < 4; r++) {
      int m = m0 + wv * 16 + quad * 4 + r;
      if (m < M) {
        float v = acc[j][r] + bv;
        if (omode == 2) {
          int bq = m >> 10, hw = m & 1023;
          size_t oi = ((size_t)bq * N + n) * 1024 + hw;
          ((float*)outp)[oi] = v + res[oi];
        } else {
          if (res) v += res[(size_t)m * N + n];
          if (omode == 1) ((unsigned short*)outp)[(size_t)m * N + n] = f2bf(v);
          else {
            ((float*)outp)[(size_t)m * N + n] = v;
            if (omode == 4) ((unsigned short*)outp2)[(size_t)m * N + n] = f2bf(v);
          }
        }
      }
    }
  }
}

// ---------------- split-K(4) MFMA flash attention: 1024 keys, 4 splits of 256 ----------------
// Double-buffered K/V staging (async-STAGE split): issue next tile's global loads, compute
// current tile (hides latency), ds_write staged regs, one barrier per tile.
#define VSTR 72
__global__ __launch_bounds__(256) void mfattns_kernel(const unsigned short* __restrict__ qp, int qstr,
                                                      const unsigned short* __restrict__ kp, int kstr,
                                                      const unsigned short* __restrict__ vp, int vstr,
                                                      const float* __restrict__ bias,
                                                      float* __restrict__ Opart,
                                                      float* __restrict__ mpart,
                                                      float* __restrict__ lpart) {
  __shared__ unsigned short Ks[2][64 * 56];
  __shared__ unsigned short Vt[2][48 * VSTR];
  __shared__ unsigned short Ps[4][16 * 72];
  int tid = threadIdx.x;
  int lane = tid & 63;
  int wv = tid >> 6;
  int quad = lane >> 4;
  int col = lane & 15;
  int bid = blockIdx.x;
  int split = bid & 3;
  int qt = (bid >> 2) & 15;
  int h = (bid >> 6) & 7;
  int b = bid >> 9;

  short8 zero8 = {0, 0, 0, 0, 0, 0, 0, 0};
  int qrow = qt * 64 + wv * 16 + col;
  const unsigned short* qbase = qp + (size_t)(b * 1024 + qrow) * qstr + h * DH;
  short8 qf0 = *(const short8*)(qbase + quad * 8);
  short8 qf1 = (quad == 0) ? *(const short8*)(qbase + 32) : zero8;

  // thread-constant staging geometry (hoisted out of tile loop)
  int kkey0 = tid / 6, ks0 = tid - kkey0 * 6;
  int u1 = tid + 256;
  int kkey1 = u1 / 6, ks1 = u1 - kkey1 * 6;   // valid iff tid < 128
  int act1 = tid < 128;
  int vs0 = tid >> 6, vkey = tid & 63;
  int vs1 = vs0 + 4;                           // valid iff tid < 128
  const unsigned short* kth0 = kp + (size_t)(b * 1024 + kkey0) * kstr + h * DH + ks0 * 8;
  const unsigned short* kth1 = kp + (size_t)(b * 1024 + kkey1) * kstr + h * DH + ks1 * 8;
  const unsigned short* vth0 = vp + (size_t)(b * 1024 + vkey) * vstr + h * DH + vs0 * 8;
  const unsigned short* vth1 = vp + (size_t)(b * 1024 + vkey) * vstr + h * DH + vs1 * 8;
  int kso0 = kkey0 * 56 + ks0 * 8;
  int kso1 = kkey1 * 56 + ks1 * 8;
  int kb0 = split * 256;
  const float* biasb = bias ? (bias + b * 1024) : nullptr;

  float4v Oacc[3];
  float4v fzero = {0.f, 0.f, 0.f, 0.f};
  Oacc[0] = fzero; Oacc[1] = fzero; Oacc[2] = fzero;
  float mr[4] = {-3.4e38f, -3.4e38f, -3.4e38f, -3.4e38f};
  float lr[4] = {0.f, 0.f, 0.f, 0.f};

  // prologue: stage tile 0 into buf 0
  {
    size_t ko = (size_t)kb0 * kstr, vo = (size_t)kb0 * vstr;
    short8 k0v = (ks0 < 5) ? *(const short8*)(kth0 + ko) : zero8;
    short8 k1v = (act1 && ks1 < 5) ? *(const short8*)(kth1 + ko) : zero8;
    short8 v0v = *(const short8*)(vth0 + vo);   // vs0 in 0..3, always valid
    short8 v1v = (act1 && vs1 < 5) ? *(const short8*)(vth1 + vo) : zero8;
    *(short8*)&Ks[0][kso0] = k0v;
    if (act1) *(short8*)&Ks[0][kso1] = k1v;
#pragma unroll
    for (int j = 0; j < 8; j++) Vt[0][(vs0 * 8 + j) * VSTR + vkey] = (unsigned short)v0v[j];
    if (act1) {
#pragma unroll
      for (int j = 0; j < 8; j++) Vt[0][(vs1 * 8 + j) * VSTR + vkey] = (unsigned short)v1v[j];
    }
  }
  __syncthreads();

#pragma unroll
  for (int t = 0; t < 4; t++) {
    int cur = t & 1;
    int kb = kb0 + t * 64;
    // issue next tile's global loads (latency hidden under this tile's compute)
    short8 nk0 = zero8, nk1 = zero8, nv0 = zero8, nv1 = zero8;
    if (t < 3) {
      size_t ko = (size_t)(kb + 64) * kstr, vo = (size_t)(kb + 64) * vstr;
      if (ks0 < 5) nk0 = *(const short8*)(kth0 + ko);
      if (act1 && ks1 < 5) nk1 = *(const short8*)(kth1 + ko);
      nv0 = *(const short8*)(vth0 + vo);
      if (act1 && vs1 < 5) nv1 = *(const short8*)(vth1 + vo);
    }
    // ---- compute tile t from buf cur ----
    float4v sf[4];
#pragma unroll
    for (int jb = 0; jb < 4; jb++) {
      const unsigned short* krow = &Ks[cur][(jb * 16 + col) * 56];
      short8 bk0 = *(const short8*)(krow + quad * 8);
      short8 bk1 = (quad == 0) ? *(const short8*)(krow + 32) : zero8;
      float4v s = fzero;
      s = __builtin_amdgcn_mfma_f32_16x16x32_bf16(qf0, bk0, s, 0, 0, 0);
      s = __builtin_amdgcn_mfma_f32_16x16x32_bf16(qf1, bk1, s, 0, 0, 0);
      float bv = biasb ? biasb[kb + jb * 16 + col] : 0.f;
#pragma unroll
      for (int r = 0; r < 4; r++) s[r] = s[r] * SCALE + bv;
      sf[jb] = s;
    }
    float tmax[4];
#pragma unroll
    for (int r = 0; r < 4; r++) {
      float tm = fmaxf(fmaxf(sf[0][r], sf[1][r]), fmaxf(sf[2][r], sf[3][r]));
#pragma unroll
      for (int o = 1; o < 16; o <<= 1) tm = fmaxf(tm, __shfl_xor(tm, o));
      tmax[r] = tm;
    }
    float al[4];
#pragma unroll
    for (int r = 0; r < 4; r++) {
      float mnew = fmaxf(mr[r], tmax[r]);
      al[r] = __expf(mr[r] - mnew);
      mr[r] = mnew;
      lr[r] *= al[r];
    }
#pragma unroll
    for (int nb = 0; nb < 3; nb++)
#pragma unroll
      for (int r = 0; r < 4; r++) Oacc[nb][r] *= al[r];
    float rs[4] = {0.f, 0.f, 0.f, 0.f};
#pragma unroll
    for (int jb = 0; jb < 4; jb++) {
#pragma unroll
      for (int r = 0; r < 4; r++) {
        float p = __expf(sf[jb][r] - mr[r]);
        rs[r] += p;
        Ps[wv][(quad * 4 + r) * 72 + jb * 16 + col] = f2bf(p);
      }
    }
#pragma unroll
    for (int r = 0; r < 4; r++) {
      float tt = rs[r];
#pragma unroll
      for (int o = 1; o < 16; o <<= 1) tt += __shfl_xor(tt, o);
      lr[r] += tt;
    }
#pragma unroll
    for (int kc = 0; kc < 2; kc++) {
      int koff = kc * 32 + quad * 8;
      short8 pa = *(const short8*)&Ps[wv][col * 72 + koff];
#pragma unroll
      for (int nb = 0; nb < 3; nb++) {
        short8 vb = *(const short8*)&Vt[cur][(nb * 16 + col) * VSTR + koff];
        Oacc[nb] = __builtin_amdgcn_mfma_f32_16x16x32_bf16(pa, vb, Oacc[nb], 0, 0, 0);
      }
    }
    // ---- write staged regs into the other buffer ----
    if (t < 3) {
      int nxt = cur ^ 1;
      *(short8*)&Ks[nxt][kso0] = nk0;
      if (act1) *(short8*)&Ks[nxt][kso1] = nk1;
#pragma unroll
      for (int j = 0; j < 8; j++) Vt[nxt][(vs0 * 8 + j) * VSTR + vkey] = (unsigned short)nv0[j];
      if (act1) {
#pragma unroll
        for (int j = 0; j < 8; j++) Vt[nxt][(vs1 * 8 + j) * VSTR + vkey] = (unsigned short)nv1[j];
      }
    }
    __syncthreads();
  }
#pragma unroll
  for (int r = 0; r < 4; r++) {
    int qo = qt * 64 + wv * 16 + quad * 4 + r;
    size_t rowidx = (size_t)(b * NH + h) * 1024 + qo;
    float* orow = Opart + (rowidx * 4 + split) * DH;
#pragma unroll
    for (int nb = 0; nb < 3; nb++) {
      int d = nb * 16 + col;
      if (d < DH) orow[d] = Oacc[nb][r];
    }
    if (col == 0) {
      mpart[rowidx * 4 + split] = mr[r];
      lpart[rowidx * 4 + split] = lr[r];
    }
  }
}

// ---------------- MFMA cross-attention Lk=77 (bf16 in, bf16 out) ----------------
// probs written transposed [(b-2)*8+h][77][1024], batches 2..3 only (the only consumers).
#define CVSTR 104
__global__ __launch_bounds__(256) void cattnm_kernel(const unsigned short* __restrict__ qp,
                                                     const unsigned short* __restrict__ kvp,
                                                     unsigned short* __restrict__ op,
                                                     float* __restrict__ probs) {
  __shared__ unsigned short Ks[80 * 56];
  __shared__ unsigned short Vt[48 * CVSTR];
  __shared__ unsigned short Ps[4][16 * 104];
  int tid = threadIdx.x;
  int lane = tid & 63;
  int wv = tid >> 6;
  int quad = lane >> 4;
  int col = lane & 15;
  int bid = blockIdx.x;
  int qt = bid & 15;
  int h = (bid >> 4) & 7;
  int b = bid >> 7;

  short8 zero8 = {0, 0, 0, 0, 0, 0, 0, 0};
  for (int u = tid; u < 480; u += 256) {
    int key = u / 6, s = u - key * 6;
    short8 v8 = zero8;
    if (s < 5 && key < 77) v8 = *(const short8*)(kvp + (size_t)(b * 77 + key) * 640 + h * DH + s * 8);
    *(short8*)&Ks[key * 56 + s * 8] = v8;
  }
  for (int u = tid; u < 576; u += 256) {
    int s = u / 96, key = u - s * 96;
    short8 v8 = zero8;
    if (s < 5 && key < 77) v8 = *(const short8*)(kvp + (size_t)(b * 77 + key) * 640 + 320 + h * DH + s * 8);
#pragma unroll
    for (int j = 0; j < 8; j++) Vt[(s * 8 + j) * CVSTR + key] = (unsigned short)v8[j];
  }
  int qrow = qt * 64 + wv * 16 + col;
  const unsigned short* qbase = qp + (size_t)(b * 1024 + qrow) * CCH + h * DH;
  short8 qf0 = *(const short8*)(qbase + quad * 8);
  short8 qf1 = (quad == 0) ? *(const short8*)(qbase + 32) : zero8;
  __syncthreads();

  float4v fzero = {0.f, 0.f, 0.f, 0.f};
  float4v sf[5];
#pragma unroll
  for (int jb = 0; jb < 5; jb++) {
    const unsigned short* krow = &Ks[(jb * 16 + col) * 56];
    short8 bk0 = *(const short8*)(krow + quad * 8);
    short8 bk1 = (quad == 0) ? *(const short8*)(krow + 32) : zero8;
    float4v s = fzero;
    s = __builtin_amdgcn_mfma_f32_16x16x32_bf16(qf0, bk0, s, 0, 0, 0);
    s = __builtin_amdgcn_mfma_f32_16x16x32_bf16(qf1, bk1, s, 0, 0, 0);
    int key = jb * 16 + col;
    float msk = (key < 77) ? 0.f : -3.4e38f;
#pragma unroll
    for (int r = 0; r < 4; r++) s[r] = s[r] * SCALE + msk;
    sf[jb] = s;
  }
  float inv[4];
#pragma unroll
  for (int r = 0; r < 4; r++) {
    float t = sf[0][r];
#pragma unroll
    for (int jb = 1; jb < 5; jb++) t = fmaxf(t, sf[jb][r]);
#pragma unroll
    for (int o = 1; o < 16; o <<= 1) t = fmaxf(t, __shfl_xor(t, o));
    float sum = 0.f;
#pragma unroll
    for (int jb = 0; jb < 5; jb++) { float e = __expf(sf[jb][r] - t); sf[jb][r] = e; sum += e; }
#pragma unroll
    for (int o = 1; o < 16; o <<= 1) sum += __shfl_xor(sum, o);
    inv[r] = 1.f / sum;
  }
#pragma unroll
  for (int jb = 0; jb < 5; jb++) {
    int key = jb * 16 + col;
    float4v pv;
#pragma unroll
    for (int r = 0; r < 4; r++) {
      float p = sf[jb][r] * inv[r];
      Ps[wv][(quad * 4 + r) * 104 + jb * 16 + col] = f2bf(p);
      pv[r] = p;
    }
    if (b >= 2 && key < 77) {
      size_t pi = ((size_t)((b - 2) * NH + h) * 77 + key) * 1024 + qt * 64 + wv * 16 + quad * 4;
      *(float4v*)&probs[pi] = pv;
    }
  }
  float4v Oacc[3];
  Oacc[0] = fzero; Oacc[1] = fzero; Oacc[2] = fzero;
#pragma unroll
  for (int kc = 0; kc < 3; kc++) {
    int koff = kc * 32 + quad * 8;
    short8 pa = (koff < 80) ? *(const short8*)&Ps[wv][col * 104 + koff] : zero8;
#pragma unroll
    for (int nb = 0; nb < 3; nb++) {
      short8 vb = *(const short8*)&Vt[(nb * 16 + col) * CVSTR + koff];
      Oacc[nb] = __builtin_amdgcn_mfma_f32_16x16x32_bf16(pa, vb, Oacc[nb], 0, 0, 0);
    }
  }
#pragma unroll
  for (int r = 0; r < 4; r++) {
    int qo = qt * 64 + wv * 16 + quad * 4 + r;
    unsigned short* orow = op + (size_t)(b * 1024 + qo) * CCH + h * DH;
#pragma unroll
    for (int nb = 0; nb < 3; nb++) {
      int d = nb * 16 + col;
      if (d < DH) orow[d] = f2bf(Oacc[nb][r]);
    }
  }
}

// ---------------- fused extract + loss + otsu: single-pass, register-resident ----------------
// pT layout: [(b-2)*8+h][77][1024]; reads are coalesced rows.
__global__ __launch_bounds__(256) void eol_kernel(const float* __restrict__ pT,
                                                  const int* __restrict__ phb, const int* __restrict__ pht,
                                                  const int* __restrict__ eob, const int* __restrict__ eot,
                                                  float* __restrict__ mask,
                                                  float* __restrict__ lossout) {
  __shared__ float S[4][24];
  __shared__ float shthr;
  int i = blockIdx.x, tid = threadIdx.x;
  int lane = tid & 63, wv = tid >> 6;
  int pb = phb[i], pt = pht[i], eb = eob[i], et = eot[i];
  float x[4], y[4];
#pragma unroll
  for (int j = 0; j < 4; j++) {
    int q = tid + 256 * j;
    float s1 = 0.f, s2 = 0.f;
#pragma unroll
    for (int hh = 0; hh < NH; hh++) {
      s1 += pT[((size_t)(pb * NH + hh) * 77 + pt) * 1024 + q];
      s2 += pT[((size_t)(eb * NH + hh) * 77 + et) * 1024 + q];
    }
    x[j] = s1 * 0.125f;
    y[j] = s2 * 0.125f;
  }
  float mx = fmaxf(fmaxf(x[0], x[1]), fmaxf(x[2], x[3]));
  float me = fmaxf(fmaxf(y[0], y[1]), fmaxf(y[2], y[3]));
  float mn = fminf(fminf(x[0], x[1]), fminf(x[2], x[3]));
  float sx = x[0] + x[1] + x[2] + x[3];
#pragma unroll
  for (int o = 32; o > 0; o >>= 1) {
    mx = fmaxf(mx, __shfl_xor(mx, o));
    me = fmaxf(me, __shfl_xor(me, o));
    mn = fminf(mn, __shfl_xor(mn, o));
    sx += __shfl_xor(sx, o);
  }
  if (lane == 0) { S[wv][0] = mx; S[wv][1] = me; S[wv][2] = mn; S[wv][3] = sx; }
  __syncthreads();
  mx = fmaxf(fmaxf(S[0][0], S[1][0]), fmaxf(S[2][0], S[3][0]));
  me = fmaxf(fmaxf(S[0][1], S[1][1]), fmaxf(S[2][1], S[3][1]));
  mn = fminf(fminf(S[0][2], S[1][2]), fminf(S[2][2], S[3][2]));
  sx = S[0][3] + S[1][3] + S[2][3] + S[3][3];
  float invmp = 1.f / mx, invme = 1.f / me;
  float inv = 1.f / (mx - mn);
  float lp = 0.f;
  float cnt[10], sm[10];
#pragma unroll
  for (int t = 0; t < 10; t++) { cnt[t] = 0.f; sm[t] = 0.f; }
#pragma unroll
  for (int j = 0; j < 4; j++) {
    float d = x[j] * invmp - y[j] * invme;
    lp += d * d;
    float v = (x[j] - mn) * inv;
#pragma unroll
    for (int t = 0; t < 10; t++) {
      if (v < t * 0.1f) { cnt[t] += 1.f; sm[t] += v; }
    }
  }
#pragma unroll
  for (int o = 32; o > 0; o >>= 1) {
    lp += __shfl_xor(lp, o);
#pragma unroll
    for (int t = 0; t < 10; t++) { cnt[t] += __shfl_xor(cnt[t], o); sm[t] += __shfl_xor(sm[t], o); }
  }
  __syncthreads();
  if (lane == 0) {
    S[wv][0] = lp;
#pragma unroll
    for (int t = 0; t < 10; t++) { S[wv][1 + t] = cnt[t]; S[wv][11 + t] = sm[t]; }
  }
  __syncthreads();
  if (tid == 0) {
    float lpt = S[0][0] + S[1][0] + S[2][0] + S[3][0];
    atomicAdd(lossout, lpt * (1.f / 2048.f));
    float total = (sx - 1024.f * mn) * inv;
    float gmax = -3.4e38f; int best = 0;
    for (int t = 0; t < 10; t++) {
      float c_low = S[0][1 + t] + S[1][1 + t] + S[2][1 + t] + S[3][1 + t];
      float s_low = S[0][11 + t] + S[1][11 + t] + S[2][11 + t] + S[3][11 + t];
      float c_high = 1024.f - c_low;
      float g;
      if (c_low > 0.f && c_high > 0.f) {
        float mu_l = s_low / c_low;
        float mu_h = (total - s_low) / c_high;
        float dd = mu_l - mu_h;
        g = (c_low * (1.f / 1024.f)) * (c_high * (1.f / 1024.f)) * dd * dd;
      } else g = -3.4e38f;
      if (g > gmax) { gmax = g; best = t; }
    }
    shthr = (gmax > 0.f) ? best * 0.1f : 0.f;
  }
  __syncthreads();
  float thr = shthr;
#pragma unroll
  for (int j = 0; j < 4; j++) {
    int q = tid + 256 * j;
    float v = (x[j] - mn) * inv;
    mask[i * 1024 + q] = (v < thr) ? 0.f : ((v > thr) ? 1.f : v);
  }
}

extern "C" void kernel_launch(void* const* d_in, const int* in_sizes, int n_in,
                              void* d_out, int out_size, void* d_ws, size_t ws_size,
                              hipStream_t stream) {
  auto F = [&](int i) { return (const float*)d_in[i]; };
  auto I = [&](int i) { return (const int*)d_in[i]; };

  float* ws = (float*)d_ws;
  float* h    = ws;                       // 1310720
  float* ffb  = h    + 1310720;           // attn split partials
  float* p2   = ffb  + 10485760;          // probs^T: 16*77*1024 = 1261568 (region sized 2523136)
  float* mask = p2   + 2523136;           // 2048

  float* Opart = ffb;                       // 32768*4*40 = 5242880
  float* mpart = ffb + 5242880;             // 131072
  float* lpart = ffb + 5242880 + 131072;    // 131072

  // bf16 region
  unsigned short* b16   = (unsigned short*)(mask + 2048);
  unsigned short* lnb16 = b16;                 // 1310720
  unsigned short* attb16= lnb16 + 1310720;     // 1310720
  unsigned short* actb16= attb16 + 1310720;    // 5242880
  unsigned short* qkv16 = actb16 + 5242880;    // 3932160
  unsigned short* q16   = qkv16 + 3932160;     // 1310720
  unsigned short* kv16  = q16 + 1310720;       // 1310720
  unsigned short* hb16  = kv16 + 1310720;      // 1310720 (bf16 mirror of h)
  unsigned short* wptr  = hb16 + 1310720;

  auto walloc = [&](int n) { unsigned short* p = wptr; wptr += n; return p; };
  unsigned short* pin_t  = walloc(102400);
  unsigned short* bqkv_t = walloc(307200);
  unsigned short* bow_t  = walloc(102400);
  unsigned short* bq2_t  = walloc(102400);
  unsigned short* bkv2_t = walloc(491520);
  unsigned short* bo2_t  = walloc(102400);
  unsigned short* bff1_t = walloc(819200);
  unsigned short* bff2_t = walloc(409600);
  unsigned short* iqkv_t = walloc(307200);
  unsigned short* iow_t  = walloc(102400);
  unsigned short* iq2_t  = walloc(102400);
  unsigned short* ikv2_t = walloc(204800);
  unsigned short* io2_t  = walloc(102400);
  unsigned short* iff1_t = walloc(819200);
  unsigned short* iff2_t = walloc(409600);
  unsigned short* pout_t = walloc(102400);

  float* out = (float*)d_out;

  // --- weight conversion table ---
  WTab wt;
  wt.lz = out + 1310720;   // loss slot zeroed by wconv
  int nt = 0, cnt = 0;
  auto addw = [&](const float* s, unsigned short* d, int K, int N, int perm) {
    wt.src[cnt] = s; wt.dst[cnt] = d; wt.Kd[cnt] = K; wt.Nd[cnt] = N; wt.perm[cnt] = perm;
    wt.tstart[cnt] = nt;
    nt += ((K + 31) / 32) * ((N + 31) / 32);
    cnt++;
  };
  addw(F(2), pin_t, 320, 320, 0);
  addw(F(4 + 2), bqkv_t, 320, 960, 0);
  addw(F(4 + 3), bow_t, 320, 320, 0);
  addw(F(4 + 7), bq2_t, 320, 320, 0);
  addw(F(4 + 8), bkv2_t, 768, 640, 0);
  addw(F(4 + 9), bo2_t, 320, 320, 0);
  addw(F(4 + 13), bff1_t, 320, 2560, 1);
  addw(F(4 + 15), bff2_t, 1280, 320, 0);
  addw(F(21 + 2), iqkv_t, 320, 960, 0);
  addw(F(21 + 3), iow_t, 320, 320, 0);
  addw(F(21 + 7), iq2_t, 320, 320, 0);
  addw(F(21 + 8), ikv2_t, 320, 640, 0);
  addw(F(21 + 9), io2_t, 320, 320, 0);
  addw(F(21 + 13), iff1_t, 320, 2560, 1);
  addw(F(21 + 15), iff2_t, 1280, 320, 0);
  addw(F(38), pout_t, 320, 320, 0);
  wt.tstart[16] = nt;

  wconv_kernel<<<nt, 256, 0, stream>>>(wt);

  auto gemm64 = [&](const void* A, const unsigned short* Wt, const float* bias,
                    const float* res, void* o, int M, int N, int K, int a32, int omode,
                    void* o2 = nullptr) {
    dim3 g((N + 63) / 64, (M + 63) / 64);
    mgemm64_kernel<<<g, 256, 0, stream>>>(A, Wt, bias, res, o, o2, M, N, K, a32, omode);
  };
  auto lngemm = [&](const float* A, const float* lw, const float* lb,
                    const unsigned short* Wt, unsigned short* o, int M, int N) {
    dim3 g(N / 64, M / 64);
    lngemm64_kernel<<<g, 256, 0, stream>>>(A, lw, lb, Wt, o, M, N);
  };
  auto mergegemm = [&](const unsigned short* Wt, const float* bias, int M) {
    dim3 g(5, M / 64);
    mergegemm64_kernel<<<g, 256, 0, stream>>>(Opart, mpart, lpart, Wt, bias, h, M);
  };

  // GN + transpose -> lnb16 ; pin proj -> h (f32)
  gn_kernel<<<128, 256, 0, stream>>>(F(40), F(0), F(1), lnb16);
  gemm64(lnb16, pin_t, F(3), nullptr, h, 4096, 320, 320, 0, 0);

  auto run_block = [&](int p, int Bx, bool img_block,
                       const unsigned short* qkv_t, const unsigned short* ow_t,
                       const unsigned short* q2_t, const unsigned short* kv2_t,
                       const unsigned short* o2_t, const unsigned short* ff1_t,
                       const unsigned short* ff2_t) {
    int M = Bx * 1024;
    // ln1 -> qkv (plain kfast GEMM) -> split-K(4) mfma flash self-attn -> fused merge+o-proj(+res)
    ln_kernel<<<M / 4, 256, 0, stream>>>(h, F(p + 0), F(p + 1), lnb16, M);
    gemm64(lnb16, qkv_t, nullptr, nullptr, qkv16, M, 960, 320, 0, 1);
    mfattns_kernel<<<Bx * 512, 256, 0, stream>>>(qkv16, 960, qkv16 + 320, 960, qkv16 + 640, 960,
                                                 nullptr, Opart, mpart, lpart);
    mergegemm(ow_t, F(p + 4), M);
    // fused ln2+q2 ; cross-attn
    lngemm(h, F(p + 5), F(p + 6), q2_t, q16, M, 320);
    if (!img_block) {
      gemm64(F(41), kv2_t, nullptr, nullptr, kv16, Bx * 77, 640, 768, 1, 1);   // f32 A (slow path)
      cattnm_kernel<<<Bx * 128, 256, 0, stream>>>(q16, kv16, attb16, p2);
      gemm64(attb16, o2_t, F(p + 10), h, h, M, 320, 320, 0, 0);
    } else {
      // ctx = h batches 2-3, available as bf16 mirror from block-1 ff2
      gemm64(hb16 + (size_t)2 * 1024 * 320, kv2_t, nullptr, nullptr, kv16, Bx * 1024, 640, 320, 0, 1);
      mfattns_kernel<<<Bx * 512, 256, 0, stream>>>(q16, 320, kv16, 640, kv16 + 320, 640,
                                                   mask, Opart, mpart, lpart);
      mergegemm(o2_t, F(p + 10), M);
    }
    // ln3 -> ff1 (plain GEMM + GEGLU epilogue) -> ff2 (f32 h + bf16 mirror hb16)
    ln_kernel<<<M / 4, 256, 0, stream>>>(h, F(p + 11), F(p + 12), lnb16, M);
    gemm64(lnb16, ff1_t, F(p + 14), nullptr, actb16, M, 2560, 320, 0, 3);
    gemm64(actb16, ff2_t, F(p + 16), h, h, M, 320, 1280, 0, 4, hb16);
  };

  // Block 1: all 4 batches, ctx = encoder_hidden_states, probs saved (transposed, b>=2 only)
  run_block(4, 4, false, bqkv_t, bow_t, bq2_t, bkv2_t, bo2_t, bff1_t, bff2_t);

  // fused extract + loss + otsu (loss slot zeroed in wconv)
  eol_kernel<<<2, 256, 0, stream>>>(p2, I(42), I(43), I(44), I(45), mask, out + 1310720);

  // Block 2: batches 0-1 in place, ctx = batches 2-3 of h (bf16 mirror), bias = mask
  run_block(21, 2, true, iqkv_t, iow_t, iq2_t, ikv2_t, io2_t, iff1_t, iff2_t);

  // pout proj from bf16 mirror (kfast) with fused transpose + residual epilogue
  gemm64(hb16, pout_t, F(39), F(40), out, 4096, 320, 320, 0, 2);
}

// Round 11
// 520.178 us; speedup vs baseline: 1.0966x; 1.0241x over previous
//
#include <hip/hip_runtime.h>
#include <hip/hip_bf16.h>
#include <math.h>

#define NH 8
#define DH 40
#define CCH 320
#define SCALE 0.15811388300841897f

typedef __attribute__((ext_vector_type(8))) short short8;
typedef __attribute__((ext_vector_type(4))) float float4v;

static __device__ __forceinline__ unsigned short f2bf(float x) {
  __hip_bfloat16 t = __float2bfloat16(x);
  return *reinterpret_cast<unsigned short*>(&t);
}

// async global->LDS, 16B per lane. LDS dest must be wave-uniform base; lane writes base+lane*16.
static __device__ __forceinline__ void gload16(const void* g, void* l) {
  __builtin_amdgcn_global_load_lds((__attribute__((address_space(1))) void*)g,
                                   (__attribute__((address_space(3))) void*)l, 16, 0, 0);
}

// ---------------- GroupNorm (32 groups, eps 1e-6) + transpose to (B,HW,C), bf16 out ----------------
__global__ __launch_bounds__(256) void gn_kernel(const float* __restrict__ x,
                                                 const float* __restrict__ w,
                                                 const float* __restrict__ b,
                                                 unsigned short* __restrict__ out) {
  int batch = blockIdx.x >> 5;
  int g = blockIdx.x & 31;
  const int CPG = 10;
  const float* xp = x + ((size_t)batch * CCH + g * CPG) * 1024;
  float s = 0.f, ss = 0.f;
  for (int i = threadIdx.x; i < CPG * 1024; i += 256) { float v = xp[i]; s += v; ss += v * v; }
  __shared__ float r1[256], r2[256];
  r1[threadIdx.x] = s; r2[threadIdx.x] = ss; __syncthreads();
  for (int off = 128; off > 0; off >>= 1) {
    if (threadIdx.x < off) { r1[threadIdx.x] += r1[threadIdx.x + off]; r2[threadIdx.x] += r2[threadIdx.x + off]; }
    __syncthreads();
  }
  float mu = r1[0] * (1.f / 10240.f);
  float var = r2[0] * (1.f / 10240.f) - mu * mu;
  float inv = rsqrtf(var + 1e-6f);
  for (int i = threadIdx.x; i < CPG * 1024; i += 256) {
    int ci = i >> 10; int hw = i & 1023; int c = g * CPG + ci;
    float v = (xp[i] - mu) * inv * w[c] + b[c];
    out[((size_t)batch * 1024 + hw) * CCH + c] = f2bf(v);
  }
}

// ---------------- LayerNorm over C=320, eps 1e-5, one wave per row (4 rows/block), bf16 out ----------------
__global__ __launch_bounds__(256) void ln_kernel(const float* __restrict__ x,
                                                 const float* __restrict__ w,
                                                 const float* __restrict__ b,
                                                 unsigned short* __restrict__ out, int M) {
  int row = blockIdx.x * 4 + (threadIdx.x >> 6);
  if (row >= M) return;
  const float* xp = x + (size_t)row * CCH;
  int lane = threadIdx.x & 63;
  float v[5]; float s = 0.f;
#pragma unroll
  for (int i = 0; i < 5; i++) { v[i] = xp[lane + 64 * i]; s += v[i]; }
#pragma unroll
  for (int o = 32; o > 0; o >>= 1) s += __shfl_xor(s, o);
  float mu = s * (1.f / 320.f);
  float ss = 0.f;
#pragma unroll
  for (int i = 0; i < 5; i++) { float d = v[i] - mu; ss += d * d; }
#pragma unroll
  for (int o = 32; o > 0; o >>= 1) ss += __shfl_xor(ss, o);
  float inv = rsqrtf(ss * (1.f / 320.f) + 1e-5f);
  unsigned short* op = out + (size_t)row * CCH;
#pragma unroll
  for (int i = 0; i < 5; i++) { int c = lane + 64 * i; op[c] = f2bf((v[i] - mu) * inv * w[c] + b[c]); }
}

// ---------------- weight transpose+convert: W(KxN f32) -> Wt(NxK bf16) ----------------
struct WTab {
  const float* src[16];
  unsigned short* dst[16];
  int Kd[16];
  int Nd[16];
  int perm[16];
  int tstart[17];
  float* lz;   // loss accumulator to zero
};
__global__ __launch_bounds__(256) void wconv_kernel(WTab t) {
  __shared__ float tile[32][33];
  if (blockIdx.x == 0 && threadIdx.x == 0) *t.lz = 0.f;
  int gid = blockIdx.x;
  int w = 0;
  while (w < 15 && gid >= t.tstart[w + 1]) w++;
  int local = gid - t.tstart[w];
  int K = t.Kd[w], N = t.Nd[w];
  int ntx = (N + 31) >> 5;
  int bx = local % ntx, by = local / ntx;
  int nb = bx * 32, kb = by * 32;
  const float* src = t.src[w];
  unsigned short* dst = t.dst[w];
  int doperm = t.perm[w];
  int half = N >> 1;
  int tx = threadIdx.x & 31, ty = threadIdx.x >> 5;
  for (int i = ty; i < 32; i += 8) {
    int k = kb + i, n = nb + tx;
    tile[i][tx] = (k < K && n < N) ? src[(size_t)k * N + n] : 0.f;
  }
  __syncthreads();
  for (int i = ty; i < 32; i += 8) {
    int n = nb + i, k = kb + tx;
    if (n < N && k < K) {
      int nd = n;
      if (doperm) {
        if (n < half) nd = (n >> 5) * 64 + (n & 31);
        else { int c = n - half; nd = (c >> 5) * 64 + 32 + (c & 31); }
      }
      dst[(size_t)nd * K + k] = f2bf(tile[tx][i]);
    }
  }
}

// ---------------- fused LayerNorm + bf16 MFMA GEMM 64x64, K=320 fixed ----------------
// A: f32 (M x 320); LN applied during staging. M%64==0, N%64==0. bf16 out, no bias.
__global__ __launch_bounds__(256) void lngemm64_kernel(const float* __restrict__ A,
                                                       const float* __restrict__ lnw,
                                                       const float* __restrict__ lnb,
                                                       const unsigned short* __restrict__ Bt,
                                                       unsigned short* __restrict__ outp,
                                                       int M, int N) {
  __shared__ unsigned short As[64][328];
  __shared__ unsigned short Bsd[2][64][32];
  __shared__ float Wf[320], Bf[320];
  __shared__ float Mu[64], Iv[64];
  const int K = 320;
  int tid = threadIdx.x;
  int lane = tid & 63;
  int wv = tid >> 6;
  int quad = lane >> 4;
  int col = lane & 15;
  int m0 = blockIdx.y * 64;
  int n0 = blockIdx.x * 64;
  const unsigned short* bp0 = Bt + (size_t)(n0 + (tid >> 2)) * K + (tid & 3) * 8;
  gload16(bp0, ((char*)Bsd[0]) + wv * 1024);
  for (int i = tid; i < 320; i += 256) { Wf[i] = lnw[i]; Bf[i] = lnb[i]; }
  int l32 = tid & 31;
  int rsub = tid >> 5;
  for (int it = 0; it < 8; it++) {
    int r = it * 8 + rsub;
    const float* ap = A + (size_t)(m0 + r) * K;
    float s = 0.f, ss = 0.f;
#pragma unroll
    for (int j = 0; j < 10; j++) { float v = ap[l32 + j * 32]; s += v; ss += v * v; }
#pragma unroll
    for (int o = 16; o > 0; o >>= 1) { s += __shfl_xor(s, o); ss += __shfl_xor(ss, o); }
    if (l32 == 0) {
      float mu = s * (1.f / 320.f);
      Mu[r] = mu;
      Iv[r] = rsqrtf(ss * (1.f / 320.f) - mu * mu + 1e-5f);
    }
  }
  __syncthreads();
#pragma unroll 4
  for (int i = 0; i < 20; i++) {
    int cc = i * 256 + tid;
    int r = cc / 80, c4 = cc - r * 80;
    int c = c4 * 4;
    float4 v = *(const float4*)(A + (size_t)(m0 + r) * K + c);
    float mu = Mu[r], iv = Iv[r];
    ushort4 o;
    o.x = f2bf((v.x - mu) * iv * Wf[c] + Bf[c]);
    o.y = f2bf((v.y - mu) * iv * Wf[c + 1] + Bf[c + 1]);
    o.z = f2bf((v.z - mu) * iv * Wf[c + 2] + Bf[c + 2]);
    o.w = f2bf((v.w - mu) * iv * Wf[c + 3] + Bf[c + 3]);
    *(ushort4*)&As[r][c] = o;
  }
  __syncthreads();
  float4v acc[4];
  float4v zero = {0.f, 0.f, 0.f, 0.f};
#pragma unroll
  for (int j = 0; j < 4; j++) acc[j] = zero;
  for (int t = 0; t < 10; t++) {
    if (t < 9) gload16(bp0 + (t + 1) * 32, ((char*)Bsd[(t + 1) & 1]) + wv * 1024);
    int k0 = t * 32;
    short8 af = *(short8*)&As[wv * 16 + col][k0 + quad * 8];
#pragma unroll
    for (int j = 0; j < 4; j++) {
      short8 bfr = *(short8*)&Bsd[t & 1][j * 16 + col][quad * 8];
      acc[j] = __builtin_amdgcn_mfma_f32_16x16x32_bf16(af, bfr, acc[j], 0, 0, 0);
    }
    __syncthreads();
  }
#pragma unroll
  for (int j = 0; j < 4; j++) {
    int n = n0 + j * 16 + col;
#pragma unroll
    for (int r = 0; r < 4; r++) {
      int m = m0 + wv * 16 + quad * 4 + r;
      outp[(size_t)m * N + n] = f2bf(acc[j][r]);
    }
  }
}

// ---------------- fused split-K merge + o-proj GEMM 64x64 (N=K=320), f32 out += res(in place h) ----------------
// Merge weights precomputed once per (row,head) into LDS (removes 5x redundant exp/div).
__global__ __launch_bounds__(256) void mergegemm64_kernel(const float* __restrict__ Opart,
                                                          const float* __restrict__ mpart,
                                                          const float* __restrict__ lpart,
                                                          const unsigned short* __restrict__ Bt,
                                                          const float* __restrict__ bias,
                                                          float* __restrict__ h, int M) {
  __shared__ unsigned short As[64][328];
  __shared__ unsigned short Bsd[2][64][32];
  __shared__ float Ws[512][4];   // [row*8+head][split]
  const int K = 320;
  int tid = threadIdx.x;
  int lane = tid & 63;
  int wv = tid >> 6;
  int quad = lane >> 4;
  int col = lane & 15;
  int m0 = blockIdx.y * 64;
  int n0 = blockIdx.x * 64;
  const unsigned short* bp0 = Bt + (size_t)(n0 + (tid >> 2)) * K + (tid & 3) * 8;
  gload16(bp0, ((char*)Bsd[0]) + wv * 1024);
  // phase 0: per-(row,head) merge weights
#pragma unroll
  for (int i = 0; i < 2; i++) {
    int si = i * 256 + tid;          // 0..511
    int r = si >> 3, hh = si & 7;
    int m = m0 + r, b = m >> 10, q = m & 1023;
    size_t ri = ((size_t)(b * NH + hh) * 1024 + q) * 4;
    float ma = mpart[ri], mb = mpart[ri + 1], mc = mpart[ri + 2], md = mpart[ri + 3];
    float Mx = fmaxf(fmaxf(ma, mb), fmaxf(mc, md));
    float w0 = __expf(ma - Mx), w1 = __expf(mb - Mx), w2 = __expf(mc - Mx), w3 = __expf(md - Mx);
    float L = lpart[ri] * w0 + lpart[ri + 1] * w1 + lpart[ri + 2] * w2 + lpart[ri + 3] * w3;
    float inv = 1.f / L;
    Ws[si][0] = w0 * inv; Ws[si][1] = w1 * inv; Ws[si][2] = w2 * inv; Ws[si][3] = w3 * inv;
  }
  __syncthreads();
  // merge-stage A: 64 rows x 40 8-elem chunks = 2560 chunks
#pragma unroll
  for (int i = 0; i < 10; i++) {
    int cc = i * 256 + tid;
    int r = cc / 40, c8 = cc - r * 40;
    int c = c8 * 8;
    int hh = c / 40;
    int d = c - hh * 40;
    int m = m0 + r, b = m >> 10, q = m & 1023;
    size_t ri = ((size_t)(b * NH + hh) * 1024 + q) * 4;
    int si = (r << 3) | hh;
    float w0 = Ws[si][0], w1 = Ws[si][1], w2 = Ws[si][2], w3 = Ws[si][3];
    const float* p0 = Opart + (ri + 0) * DH + d;
    const float* p1 = Opart + (ri + 1) * DH + d;
    const float* p2 = Opart + (ri + 2) * DH + d;
    const float* p3 = Opart + (ri + 3) * DH + d;
    float4 a0 = *(const float4*)p0, a1 = *(const float4*)p1, a2 = *(const float4*)p2, a3 = *(const float4*)p3;
    float4 b0 = *(const float4*)(p0 + 4), b1 = *(const float4*)(p1 + 4), b2 = *(const float4*)(p2 + 4), b3 = *(const float4*)(p3 + 4);
    ushort4 u0, u1;
    u0.x = f2bf(a0.x * w0 + a1.x * w1 + a2.x * w2 + a3.x * w3);
    u0.y = f2bf(a0.y * w0 + a1.y * w1 + a2.y * w2 + a3.y * w3);
    u0.z = f2bf(a0.z * w0 + a1.z * w1 + a2.z * w2 + a3.z * w3);
    u0.w = f2bf(a0.w * w0 + a1.w * w1 + a2.w * w2 + a3.w * w3);
    u1.x = f2bf(b0.x * w0 + b1.x * w1 + b2.x * w2 + b3.x * w3);
    u1.y = f2bf(b0.y * w0 + b1.y * w1 + b2.y * w2 + b3.y * w3);
    u1.z = f2bf(b0.z * w0 + b1.z * w1 + b2.z * w2 + b3.z * w3);
    u1.w = f2bf(b0.w * w0 + b1.w * w1 + b2.w * w2 + b3.w * w3);
    *(ushort4*)&As[r][c] = u0;
    *(ushort4*)&As[r][c + 4] = u1;
  }
  __syncthreads();
  float4v acc[4];
  float4v zero = {0.f, 0.f, 0.f, 0.f};
#pragma unroll
  for (int j = 0; j < 4; j++) acc[j] = zero;
  for (int t = 0; t < 10; t++) {
    if (t < 9) gload16(bp0 + (t + 1) * 32, ((char*)Bsd[(t + 1) & 1]) + wv * 1024);
    int k0 = t * 32;
    short8 af = *(short8*)&As[wv * 16 + col][k0 + quad * 8];
#pragma unroll
    for (int j = 0; j < 4; j++) {
      short8 bfr = *(short8*)&Bsd[t & 1][j * 16 + col][quad * 8];
      acc[j] = __builtin_amdgcn_mfma_f32_16x16x32_bf16(af, bfr, acc[j], 0, 0, 0);
    }
    __syncthreads();
  }
#pragma unroll
  for (int j = 0; j < 4; j++) {
    int n = n0 + j * 16 + col;
    float bv = bias[n];
#pragma unroll
    for (int r = 0; r < 4; r++) {
      int m = m0 + wv * 16 + quad * 4 + r;
      size_t oi = (size_t)m * 320 + n;
      h[oi] = acc[j][r] + bv + h[oi];
    }
  }
}

// ---------------- bf16 MFMA GEMM 64x64, BK=160; a32: f32 A staging (slow path) ----------------
// omode: 0=f32 out, 1=bf16 out, 2=transpose+residual f32 out, 3=GEGLU epilogue (bf16, width N/2),
//        4=f32 out (+res) to outp AND bf16 mirror to outp2
__global__ __launch_bounds__(256) void mgemm64_kernel(const void* __restrict__ Ap,
                                                      const unsigned short* __restrict__ Bt,
                                                      const float* __restrict__ bias,
                                                      const float* __restrict__ res,
                                                      void* __restrict__ outp,
                                                      void* __restrict__ outp2,
                                                      int M, int N, int K, int a32, int omode) {
  __shared__ unsigned short As[64][160];
  __shared__ unsigned short Bs[64][160];
  int tid = threadIdx.x;
  int lane = tid & 63;
  int wv = tid >> 6;
  int quad = lane >> 4;
  int col = lane & 15;
  int m0 = blockIdx.y * 64;
  int n0 = blockIdx.x * 64;
  float4v acc[4];
  float4v zero = {0.f, 0.f, 0.f, 0.f};
#pragma unroll
  for (int j = 0; j < 4; j++) acc[j] = zero;
  short8 vzero = {0, 0, 0, 0, 0, 0, 0, 0};
  int kfast = (!a32) && ((K % 160) == 0);
  int off[5];
#pragma unroll
  for (int i = 0; i < 5; i++) { int c = i * 256 + tid; int row = c / 20; off[i] = row * K + (c - row * 20) * 8; }
  int wb = (tid & 192) * 16;   // wave*1024: uniform LDS base for this wave's chunk run
  const unsigned short* Ab = (const unsigned short*)Ap + (size_t)m0 * K;
  const unsigned short* Bb = Bt + (size_t)n0 * K;
  for (int k0 = 0; k0 < K; k0 += 160) {
    if (kfast) {
#pragma unroll
      for (int i = 0; i < 5; i++) {
        gload16(Ab + off[i] + k0, ((char*)As) + wb + i * 4096);
        gload16(Bb + off[i] + k0, ((char*)Bs) + wb + i * 4096);
      }
    } else {
#pragma unroll
      for (int i = 0; i < 5; i++) {
        int u = tid + i * 256;            // 0..1279
        int row = u / 20, seg = u - row * 20;
        int k = k0 + seg * 8;
        int m = m0 + row;
        short8 av = vzero;
        if (m < M && k < K) {
          if (a32) {
            const float* Af = (const float*)Ap;
            float4 f0 = *(const float4*)(Af + (size_t)m * K + k);
            float4 f1 = *(const float4*)(Af + (size_t)m * K + k + 4);
            av[0] = (short)f2bf(f0.x); av[1] = (short)f2bf(f0.y);
            av[2] = (short)f2bf(f0.z); av[3] = (short)f2bf(f0.w);
            av[4] = (short)f2bf(f1.x); av[5] = (short)f2bf(f1.y);
            av[6] = (short)f2bf(f1.z); av[7] = (short)f2bf(f1.w);
          } else {
            av = *(const short8*)((const unsigned short*)Ap + (size_t)m * K + k);
          }
        }
        *(short8*)&As[row][seg * 8] = av;
        int n = n0 + row;
        short8 bv = vzero;
        if (n < N && k < K) bv = *(const short8*)(Bt + (size_t)n * K + k);
        *(short8*)&Bs[row][seg * 8] = bv;
      }
    }
    __syncthreads();
#pragma unroll
    for (int kk = 0; kk < 5; kk++) {
      int kq2 = kk * 32 + quad * 8;
      short8 af = *(short8*)&As[wv * 16 + col][kq2];
#pragma unroll
      for (int j = 0; j < 4; j++) {
        short8 bfr = *(short8*)&Bs[j * 16 + col][kq2];
        acc[j] = __builtin_amdgcn_mfma_f32_16x16x32_bf16(af, bfr, acc[j], 0, 0, 0);
      }
    }
    __syncthreads();
  }
  if (omode == 3) {
    // GEGLU: permuted 64-wide weight groups [a(32)|g(32)]; j=0,1 -> 'a', j=2,3 -> 'g'
    int half = N >> 1;
#pragma unroll
    for (int jb = 0; jb < 2; jb++) {
      int nout = (n0 >> 1) + jb * 16 + col;
      float ba = bias[nout];
      float bg = bias[half + nout];
#pragma unroll
      for (int r = 0; r < 4; r++) {
        int m = m0 + wv * 16 + quad * 4 + r;
        if (m < M) {
          float a = acc[jb][r] + ba;
          float g = acc[jb + 2][r] + bg;
          float t2 = tanhf(0.7978845608028654f * (g + 0.044715f * g * g * g));
          ((unsigned short*)outp)[(size_t)m * half + nout] = f2bf(a * (0.5f * g * (1.f + t2)));
        }
      }
    }
    return;
  }
#pragma unroll
  for (int j = 0; j < 4; j++) {
    int n = n0 + j * 16 + col;
    if (n >= N) continue;
    float bv = bias ? bias[n] : 0.f;
#pragma unroll
    for (int r = 0; r < 4; r++) {
      int m = m0 + wv * 16 + quad * 4 + r;
      if (m < M) {
        float v = acc[j][r] + bv;
        if (omode == 2) {
          int bq = m >> 10, hw = m & 1023;
          size_t oi = ((size_t)bq * N + n) * 1024 + hw;
          ((float*)outp)[oi] = v + res[oi];
        } else {
          if (res) v += res[(size_t)m * N + n];
          if (omode == 1) ((unsigned short*)outp)[(size_t)m * N + n] = f2bf(v);
          else {
            ((float*)outp)[(size_t)m * N + n] = v;
            if (omode == 4) ((unsigned short*)outp2)[(size_t)m * N + n] = f2bf(v);
          }
        }
      }
    }
  }
}

// ---------------- split-K(4) MFMA flash attention: 1024 keys, 4 splits of 256 ----------------
// Defer-max (T13): skip running-max update + O rescale when per-tile max growth <= 8
// (exact math: online softmax is invariant to the max reference; P bounded by e^8).
#define VSTR 72
__global__ __launch_bounds__(256) void mfattns_kernel(const unsigned short* __restrict__ qp, int qstr,
                                                      const unsigned short* __restrict__ kp, int kstr,
                                                      const unsigned short* __restrict__ vp, int vstr,
                                                      const float* __restrict__ bias,
                                                      float* __restrict__ Opart,
                                                      float* __restrict__ mpart,
                                                      float* __restrict__ lpart) {
  __shared__ unsigned short Ks[64 * 56];
  __shared__ unsigned short Vt[48 * VSTR];
  __shared__ unsigned short Ps[4][16 * 72];
  int tid = threadIdx.x;
  int lane = tid & 63;
  int wv = tid >> 6;
  int quad = lane >> 4;
  int col = lane & 15;
  int bid = blockIdx.x;
  int split = bid & 3;
  int qt = (bid >> 2) & 15;
  int h = (bid >> 6) & 7;
  int b = bid >> 9;

  short8 zero8 = {0, 0, 0, 0, 0, 0, 0, 0};
  int qrow = qt * 64 + wv * 16 + col;
  const unsigned short* qbase = qp + (size_t)(b * 1024 + qrow) * qstr + h * DH;
  short8 qf0 = *(const short8*)(qbase + quad * 8);
  short8 qf1 = (quad == 0) ? *(const short8*)(qbase + 32) : zero8;

  float4v Oacc[3];
  float4v fzero = {0.f, 0.f, 0.f, 0.f};
  Oacc[0] = fzero; Oacc[1] = fzero; Oacc[2] = fzero;
  float mr[4] = {-3.4e38f, -3.4e38f, -3.4e38f, -3.4e38f};
  float lr[4] = {0.f, 0.f, 0.f, 0.f};

  for (int kt = split * 4; kt < split * 4 + 4; kt++) {
    int kb = kt * 64;
    __syncthreads();
    for (int u = tid; u < 384; u += 256) {
      int key = u / 6, s = u - key * 6;
      short8 kv8 = zero8;
      if (s < 5) kv8 = *(const short8*)(kp + (size_t)(b * 1024 + kb + key) * kstr + h * DH + s * 8);
      *(short8*)&Ks[key * 56 + s * 8] = kv8;
    }
    for (int u = tid; u < 384; u += 256) {
      int s = u >> 6, key = u & 63;
      short8 vv8 = zero8;
      if (s < 5) vv8 = *(const short8*)(vp + (size_t)(b * 1024 + kb + key) * vstr + h * DH + s * 8);
#pragma unroll
      for (int j = 0; j < 8; j++) Vt[(s * 8 + j) * VSTR + key] = (unsigned short)vv8[j];
    }
    __syncthreads();

    float4v sf[4];
#pragma unroll
    for (int jb = 0; jb < 4; jb++) {
      const unsigned short* krow = &Ks[(jb * 16 + col) * 56];
      short8 bk0 = *(const short8*)(krow + quad * 8);
      short8 bk1 = (quad == 0) ? *(const short8*)(krow + 32) : zero8;
      float4v s = fzero;
      s = __builtin_amdgcn_mfma_f32_16x16x32_bf16(qf0, bk0, s, 0, 0, 0);
      s = __builtin_amdgcn_mfma_f32_16x16x32_bf16(qf1, bk1, s, 0, 0, 0);
      float bv = bias ? bias[b * 1024 + kb + jb * 16 + col] : 0.f;
#pragma unroll
      for (int r = 0; r < 4; r++) s[r] = s[r] * SCALE + bv;
      sf[jb] = s;
    }
    float tmax[4];
#pragma unroll
    for (int r = 0; r < 4; r++) {
      float t = fmaxf(fmaxf(sf[0][r], sf[1][r]), fmaxf(sf[2][r], sf[3][r]));
#pragma unroll
      for (int o = 1; o < 16; o <<= 1) t = fmaxf(t, __shfl_xor(t, o));
      tmax[r] = t;
    }
    // T13 defer-max: only rescale when some row's max grew by > 8
    float grow = fmaxf(fmaxf(tmax[0] - mr[0], tmax[1] - mr[1]),
                       fmaxf(tmax[2] - mr[2], tmax[3] - mr[3]));
    if (!__all(grow <= 8.f)) {
      float al[4];
#pragma unroll
      for (int r = 0; r < 4; r++) {
        float mnew = fmaxf(mr[r], tmax[r]);
        al[r] = __expf(mr[r] - mnew);
        mr[r] = mnew;
        lr[r] *= al[r];
      }
#pragma unroll
      for (int nb = 0; nb < 3; nb++)
#pragma unroll
        for (int r = 0; r < 4; r++) Oacc[nb][r] *= al[r];
    }
    float rs[4] = {0.f, 0.f, 0.f, 0.f};
#pragma unroll
    for (int jb = 0; jb < 4; jb++) {
#pragma unroll
      for (int r = 0; r < 4; r++) {
        float p = __expf(sf[jb][r] - mr[r]);
        rs[r] += p;
        Ps[wv][(quad * 4 + r) * 72 + jb * 16 + col] = f2bf(p);
      }
    }
#pragma unroll
    for (int r = 0; r < 4; r++) {
      float t = rs[r];
#pragma unroll
      for (int o = 1; o < 16; o <<= 1) t += __shfl_xor(t, o);
      lr[r] += t;
    }
#pragma unroll
    for (int kc = 0; kc < 2; kc++) {
      int koff = kc * 32 + quad * 8;
      short8 pa = *(const short8*)&Ps[wv][col * 72 + koff];
#pragma unroll
      for (int nb = 0; nb < 3; nb++) {
        short8 vb = *(const short8*)&Vt[(nb * 16 + col) * VSTR + koff];
        Oacc[nb] = __builtin_amdgcn_mfma_f32_16x16x32_bf16(pa, vb, Oacc[nb], 0, 0, 0);
      }
    }
  }
#pragma unroll
  for (int r = 0; r < 4; r++) {
    int qo = qt * 64 + wv * 16 + quad * 4 + r;
    size_t rowidx = (size_t)(b * NH + h) * 1024 + qo;
    float* orow = Opart + (rowidx * 4 + split) * DH;
#pragma unroll
    for (int nb = 0; nb < 3; nb++) {
      int d = nb * 16 + col;
      if (d < DH) orow[d] = Oacc[nb][r];
    }
    if (col == 0) {
      mpart[rowidx * 4 + split] = mr[r];
      lpart[rowidx * 4 + split] = lr[r];
    }
  }
}

// ---------------- MFMA cross-attention Lk=77 (bf16 in, bf16 out) ----------------
// probs written transposed [(b-2)*8+h][77][1024], batches 2..3 only (the only consumers).
#define CVSTR 104
__global__ __launch_bounds__(256) void cattnm_kernel(const unsigned short* __restrict__ qp,
                                                     const unsigned short* __restrict__ kvp,
                                                     unsigned short* __restrict__ op,
                                                     float* __restrict__ probs) {
  __shared__ unsigned short Ks[80 * 56];
  __shared__ unsigned short Vt[48 * CVSTR];
  __shared__ unsigned short Ps[4][16 * 104];
  int tid = threadIdx.x;
  int lane = tid & 63;
  int wv = tid >> 6;
  int quad = lane >> 4;
  int col = lane & 15;
  int bid = blockIdx.x;
  int qt = bid & 15;
  int h = (bid >> 4) & 7;
  int b = bid >> 7;

  short8 zero8 = {0, 0, 0, 0, 0, 0, 0, 0};
  for (int u = tid; u < 480; u += 256) {
    int key = u / 6, s = u - key * 6;
    short8 v8 = zero8;
    if (s < 5 && key < 77) v8 = *(const short8*)(kvp + (size_t)(b * 77 + key) * 640 + h * DH + s * 8);
    *(short8*)&Ks[key * 56 + s * 8] = v8;
  }
  for (int u = tid; u < 576; u += 256) {
    int s = u / 96, key = u - s * 96;
    short8 v8 = zero8;
    if (s < 5 && key < 77) v8 = *(const short8*)(kvp + (size_t)(b * 77 + key) * 640 + 320 + h * DH + s * 8);
#pragma unroll
    for (int j = 0; j < 8; j++) Vt[(s * 8 + j) * CVSTR + key] = (unsigned short)v8[j];
  }
  int qrow = qt * 64 + wv * 16 + col;
  const unsigned short* qbase = qp + (size_t)(b * 1024 + qrow) * CCH + h * DH;
  short8 qf0 = *(const short8*)(qbase + quad * 8);
  short8 qf1 = (quad == 0) ? *(const short8*)(qbase + 32) : zero8;
  __syncthreads();

  float4v fzero = {0.f, 0.f, 0.f, 0.f};
  float4v sf[5];
#pragma unroll
  for (int jb = 0; jb < 5; jb++) {
    const unsigned short* krow = &Ks[(jb * 16 + col) * 56];
    short8 bk0 = *(const short8*)(krow + quad * 8);
    short8 bk1 = (quad == 0) ? *(const short8*)(krow + 32) : zero8;
    float4v s = fzero;
    s = __builtin_amdgcn_mfma_f32_16x16x32_bf16(qf0, bk0, s, 0, 0, 0);
    s = __builtin_amdgcn_mfma_f32_16x16x32_bf16(qf1, bk1, s, 0, 0, 0);
    int key = jb * 16 + col;
    float msk = (key < 77) ? 0.f : -3.4e38f;
#pragma unroll
    for (int r = 0; r < 4; r++) s[r] = s[r] * SCALE + msk;
    sf[jb] = s;
  }
  float inv[4];
#pragma unroll
  for (int r = 0; r < 4; r++) {
    float t = sf[0][r];
#pragma unroll
    for (int jb = 1; jb < 5; jb++) t = fmaxf(t, sf[jb][r]);
#pragma unroll
    for (int o = 1; o < 16; o <<= 1) t = fmaxf(t, __shfl_xor(t, o));
    float sum = 0.f;
#pragma unroll
    for (int jb = 0; jb < 5; jb++) { float e = __expf(sf[jb][r] - t); sf[jb][r] = e; sum += e; }
#pragma unroll
    for (int o = 1; o < 16; o <<= 1) sum += __shfl_xor(sum, o);
    inv[r] = 1.f / sum;
  }
#pragma unroll
  for (int jb = 0; jb < 5; jb++) {
    int key = jb * 16 + col;
    float4v pv;
#pragma unroll
    for (int r = 0; r < 4; r++) {
      float p = sf[jb][r] * inv[r];
      Ps[wv][(quad * 4 + r) * 104 + jb * 16 + col] = f2bf(p);
      pv[r] = p;
    }
    if (b >= 2 && key < 77) {
      size_t pi = ((size_t)((b - 2) * NH + h) * 77 + key) * 1024 + qt * 64 + wv * 16 + quad * 4;
      *(float4v*)&probs[pi] = pv;
    }
  }
  float4v Oacc[3];
  Oacc[0] = fzero; Oacc[1] = fzero; Oacc[2] = fzero;
#pragma unroll
  for (int kc = 0; kc < 3; kc++) {
    int koff = kc * 32 + quad * 8;
    short8 pa = (koff < 80) ? *(const short8*)&Ps[wv][col * 104 + koff] : zero8;
#pragma unroll
    for (int nb = 0; nb < 3; nb++) {
      short8 vb = *(const short8*)&Vt[(nb * 16 + col) * CVSTR + koff];
      Oacc[nb] = __builtin_amdgcn_mfma_f32_16x16x32_bf16(pa, vb, Oacc[nb], 0, 0, 0);
    }
  }
#pragma unroll
  for (int r = 0; r < 4; r++) {
    int qo = qt * 64 + wv * 16 + quad * 4 + r;
    unsigned short* orow = op + (size_t)(b * 1024 + qo) * CCH + h * DH;
#pragma unroll
    for (int nb = 0; nb < 3; nb++) {
      int d = nb * 16 + col;
      if (d < DH) orow[d] = f2bf(Oacc[nb][r]);
    }
  }
}

// ---------------- fused extract + loss + otsu: single-pass, register-resident ----------------
// pT layout: [(b-2)*8+h][77][1024]; reads are coalesced rows.
__global__ __launch_bounds__(256) void eol_kernel(const float* __restrict__ pT,
                                                  const int* __restrict__ phb, const int* __restrict__ pht,
                                                  const int* __restrict__ eob, const int* __restrict__ eot,
                                                  float* __restrict__ mask,
                                                  float* __restrict__ lossout) {
  __shared__ float S[4][24];
  __shared__ float shthr;
  int i = blockIdx.x, tid = threadIdx.x;
  int lane = tid & 63, wv = tid >> 6;
  int pb = phb[i], pt = pht[i], eb = eob[i], et = eot[i];
  float x[4], y[4];
#pragma unroll
  for (int j = 0; j < 4; j++) {
    int q = tid + 256 * j;
    float s1 = 0.f, s2 = 0.f;
#pragma unroll
    for (int hh = 0; hh < NH; hh++) {
      s1 += pT[((size_t)(pb * NH + hh) * 77 + pt) * 1024 + q];
      s2 += pT[((size_t)(eb * NH + hh) * 77 + et) * 1024 + q];
    }
    x[j] = s1 * 0.125f;
    y[j] = s2 * 0.125f;
  }
  float mx = fmaxf(fmaxf(x[0], x[1]), fmaxf(x[2], x[3]));
  float me = fmaxf(fmaxf(y[0], y[1]), fmaxf(y[2], y[3]));
  float mn = fminf(fminf(x[0], x[1]), fminf(x[2], x[3]));
  float sx = x[0] + x[1] + x[2] + x[3];
#pragma unroll
  for (int o = 32; o > 0; o >>= 1) {
    mx = fmaxf(mx, __shfl_xor(mx, o));
    me = fmaxf(me, __shfl_xor(me, o));
    mn = fminf(mn, __shfl_xor(mn, o));
    sx += __shfl_xor(sx, o);
  }
  if (lane == 0) { S[wv][0] = mx; S[wv][1] = me; S[wv][2] = mn; S[wv][3] = sx; }
  __syncthreads();
  mx = fmaxf(fmaxf(S[0][0], S[1][0]), fmaxf(S[2][0], S[3][0]));
  me = fmaxf(fmaxf(S[0][1], S[1][1]), fmaxf(S[2][1], S[3][1]));
  mn = fminf(fminf(S[0][2], S[1][2]), fminf(S[2][2], S[3][2]));
  sx = S[0][3] + S[1][3] + S[2][3] + S[3][3];
  float invmp = 1.f / mx, invme = 1.f / me;
  float inv = 1.f / (mx - mn);
  float lp = 0.f;
  float cnt[10], sm[10];
#pragma unroll
  for (int t = 0; t < 10; t++) { cnt[t] = 0.f; sm[t] = 0.f; }
#pragma unroll
  for (int j = 0; j < 4; j++) {
    float d = x[j] * invmp - y[j] * invme;
    lp += d * d;
    float v = (x[j] - mn) * inv;
#pragma unroll
    for (int t = 0; t < 10; t++) {
      if (v < t * 0.1f) { cnt[t] += 1.f; sm[t] += v; }
    }
  }
#pragma unroll
  for (int o = 32; o > 0; o >>= 1) {
    lp += __shfl_xor(lp, o);
#pragma unroll
    for (int t = 0; t < 10; t++) { cnt[t] += __shfl_xor(cnt[t], o); sm[t] += __shfl_xor(sm[t], o); }
  }
  __syncthreads();
  if (lane == 0) {
    S[wv][0] = lp;
#pragma unroll
    for (int t = 0; t < 10; t++) { S[wv][1 + t] = cnt[t]; S[wv][11 + t] = sm[t]; }
  }
  __syncthreads();
  if (tid == 0) {
    float lpt = S[0][0] + S[1][0] + S[2][0] + S[3][0];
    atomicAdd(lossout, lpt * (1.f / 2048.f));
    float total = (sx - 1024.f * mn) * inv;
    float gmax = -3.4e38f; int best = 0;
    for (int t = 0; t < 10; t++) {
      float c_low = S[0][1 + t] + S[1][1 + t] + S[2][1 + t] + S[3][1 + t];
      float s_low = S[0][11 + t] + S[1][11 + t] + S[2][11 + t] + S[3][11 + t];
      float c_high = 1024.f - c_low;
      float g;
      if (c_low > 0.f && c_high > 0.f) {
        float mu_l = s_low / c_low;
        float mu_h = (total - s_low) / c_high;
        float dd = mu_l - mu_h;
        g = (c_low * (1.f / 1024.f)) * (c_high * (1.f / 1024.f)) * dd * dd;
      } else g = -3.4e38f;
      if (g > gmax) { gmax = g; best = t; }
    }
    shthr = (gmax > 0.f) ? best * 0.1f : 0.f;
  }
  __syncthreads();
  float thr = shthr;
#pragma unroll
  for (int j = 0; j < 4; j++) {
    int q = tid + 256 * j;
    float v = (x[j] - mn) * inv;
    mask[i * 1024 + q] = (v < thr) ? 0.f : ((v > thr) ? 1.f : v);
  }
}

extern "C" void kernel_launch(void* const* d_in, const int* in_sizes, int n_in,
                              void* d_out, int out_size, void* d_ws, size_t ws_size,
                              hipStream_t stream) {
  auto F = [&](int i) { return (const float*)d_in[i]; };
  auto I = [&](int i) { return (const int*)d_in[i]; };

  float* ws = (float*)d_ws;
  float* h    = ws;                       // 1310720
  float* ffb  = h    + 1310720;           // attn split partials
  float* p2   = ffb  + 10485760;          // probs^T: 16*77*1024 = 1261568 (region sized 2523136)
  float* mask = p2   + 2523136;           // 2048

  float* Opart = ffb;                       // 32768*4*40 = 5242880
  float* mpart = ffb + 5242880;             // 131072
  float* lpart = ffb + 5242880 + 131072;    // 131072

  // bf16 region
  unsigned short* b16   = (unsigned short*)(mask + 2048);
  unsigned short* lnb16 = b16;                 // 1310720
  unsigned short* attb16= lnb16 + 1310720;     // 1310720
  unsigned short* actb16= attb16 + 1310720;    // 5242880
  unsigned short* qkv16 = actb16 + 5242880;    // 3932160
  unsigned short* q16   = qkv16 + 3932160;     // 1310720
  unsigned short* kv16  = q16 + 1310720;       // 1310720
  unsigned short* hb16  = kv16 + 1310720;      // 1310720 (bf16 mirror of h)
  unsigned short* wptr  = hb16 + 1310720;

  auto walloc = [&](int n) { unsigned short* p = wptr; wptr += n; return p; };
  unsigned short* pin_t  = walloc(102400);
  unsigned short* bqkv_t = walloc(307200);
  unsigned short* bow_t  = walloc(102400);
  unsigned short* bq2_t  = walloc(102400);
  unsigned short* bkv2_t = walloc(491520);
  unsigned short* bo2_t  = walloc(102400);
  unsigned short* bff1_t = walloc(819200);
  unsigned short* bff2_t = walloc(409600);
  unsigned short* iqkv_t = walloc(307200);
  unsigned short* iow_t  = walloc(102400);
  unsigned short* iq2_t  = walloc(102400);
  unsigned short* ikv2_t = walloc(204800);
  unsigned short* io2_t  = walloc(102400);
  unsigned short* iff1_t = walloc(819200);
  unsigned short* iff2_t = walloc(409600);
  unsigned short* pout_t = walloc(102400);

  float* out = (float*)d_out;

  // --- weight conversion table ---
  WTab wt;
  wt.lz = out + 1310720;   // loss slot zeroed by wconv
  int nt = 0, cnt = 0;
  auto addw = [&](const float* s, unsigned short* d, int K, int N, int perm) {
    wt.src[cnt] = s; wt.dst[cnt] = d; wt.Kd[cnt] = K; wt.Nd[cnt] = N; wt.perm[cnt] = perm;
    wt.tstart[cnt] = nt;
    nt += ((K + 31) / 32) * ((N + 31) / 32);
    cnt++;
  };
  addw(F(2), pin_t, 320, 320, 0);
  addw(F(4 + 2), bqkv_t, 320, 960, 0);
  addw(F(4 + 3), bow_t, 320, 320, 0);
  addw(F(4 + 7), bq2_t, 320, 320, 0);
  addw(F(4 + 8), bkv2_t, 768, 640, 0);
  addw(F(4 + 9), bo2_t, 320, 320, 0);
  addw(F(4 + 13), bff1_t, 320, 2560, 1);
  addw(F(4 + 15), bff2_t, 1280, 320, 0);
  addw(F(21 + 2), iqkv_t, 320, 960, 0);
  addw(F(21 + 3), iow_t, 320, 320, 0);
  addw(F(21 + 7), iq2_t, 320, 320, 0);
  addw(F(21 + 8), ikv2_t, 320, 640, 0);
  addw(F(21 + 9), io2_t, 320, 320, 0);
  addw(F(21 + 13), iff1_t, 320, 2560, 1);
  addw(F(21 + 15), iff2_t, 1280, 320, 0);
  addw(F(38), pout_t, 320, 320, 0);
  wt.tstart[16] = nt;

  wconv_kernel<<<nt, 256, 0, stream>>>(wt);

  auto gemm64 = [&](const void* A, const unsigned short* Wt, const float* bias,
                    const float* res, void* o, int M, int N, int K, int a32, int omode,
                    void* o2 = nullptr) {
    dim3 g((N + 63) / 64, (M + 63) / 64);
    mgemm64_kernel<<<g, 256, 0, stream>>>(A, Wt, bias, res, o, o2, M, N, K, a32, omode);
  };
  auto lngemm = [&](const float* A, const float* lw, const float* lb,
                    const unsigned short* Wt, unsigned short* o, int M, int N) {
    dim3 g(N / 64, M / 64);
    lngemm64_kernel<<<g, 256, 0, stream>>>(A, lw, lb, Wt, o, M, N);
  };
  auto mergegemm = [&](const unsigned short* Wt, const float* bias, int M) {
    dim3 g(5, M / 64);
    mergegemm64_kernel<<<g, 256, 0, stream>>>(Opart, mpart, lpart, Wt, bias, h, M);
  };

  // GN + transpose -> lnb16 ; pin proj -> h (f32)
  gn_kernel<<<128, 256, 0, stream>>>(F(40), F(0), F(1), lnb16);
  gemm64(lnb16, pin_t, F(3), nullptr, h, 4096, 320, 320, 0, 0);

  auto run_block = [&](int p, int Bx, bool img_block,
                       const unsigned short* qkv_t, const unsigned short* ow_t,
                       const unsigned short* q2_t, const unsigned short* kv2_t,
                       const unsigned short* o2_t, const unsigned short* ff1_t,
                       const unsigned short* ff2_t) {
    int M = Bx * 1024;
    // ln1 -> qkv (plain kfast GEMM) -> split-K(4) mfma flash self-attn -> fused merge+o-proj(+res)
    ln_kernel<<<M / 4, 256, 0, stream>>>(h, F(p + 0), F(p + 1), lnb16, M);
    gemm64(lnb16, qkv_t, nullptr, nullptr, qkv16, M, 960, 320, 0, 1);
    mfattns_kernel<<<Bx * 512, 256, 0, stream>>>(qkv16, 960, qkv16 + 320, 960, qkv16 + 640, 960,
                                                 nullptr, Opart, mpart, lpart);
    mergegemm(ow_t, F(p + 4), M);
    // fused ln2+q2 ; cross-attn
    lngemm(h, F(p + 5), F(p + 6), q2_t, q16, M, 320);
    if (!img_block) {
      gemm64(F(41), kv2_t, nullptr, nullptr, kv16, Bx * 77, 640, 768, 1, 1);   // f32 A (slow path)
      cattnm_kernel<<<Bx * 128, 256, 0, stream>>>(q16, kv16, attb16, p2);
      gemm64(attb16, o2_t, F(p + 10), h, h, M, 320, 320, 0, 0);
    } else {
      // ctx = h batches 2-3, available as bf16 mirror from block-1 ff2
      gemm64(hb16 + (size_t)2 * 1024 * 320, kv2_t, nullptr, nullptr, kv16, Bx * 1024, 640, 320, 0, 1);
      mfattns_kernel<<<Bx * 512, 256, 0, stream>>>(q16, 320, kv16, 640, kv16 + 320, 640,
                                                   mask, Opart, mpart, lpart);
      mergegemm(o2_t, F(p + 10), M);
    }
    // ln3 -> ff1 (plain GEMM + GEGLU epilogue) -> ff2 (f32 h + bf16 mirror hb16)
    ln_kernel<<<M / 4, 256, 0, stream>>>(h, F(p + 11), F(p + 12), lnb16, M);
    gemm64(lnb16, ff1_t, F(p + 14), nullptr, actb16, M, 2560, 320, 0, 3);
    gemm64(actb16, ff2_t, F(p + 16), h, h, M, 320, 1280, 0, 4, hb16);
  };

  // Block 1: all 4 batches, ctx = encoder_hidden_states, probs saved (transposed, b>=2 only)
  run_block(4, 4, false, bqkv_t, bow_t, bq2_t, bkv2_t, bo2_t, bff1_t, bff2_t);

  // fused extract + loss + otsu (loss slot zeroed in wconv)
  eol_kernel<<<2, 256, 0, stream>>>(p2, I(42), I(43), I(44), I(45), mask, out + 1310720);

  // Block 2: batches 0-1 in place, ctx = batches 2-3 of h (bf16 mirror), bias = mask
  run_block(21, 2, true, iqkv_t, iow_t, iq2_t, ikv2_t, io2_t, iff1_t, iff2_t);

  // pout proj from bf16 mirror (kfast) with fused transpose + residual epilogue
  gemm64(hb16, pout_t, F(39), F(40), out, 4096, 320, 320, 0, 2);
}